// Round 4
// baseline (400.229 us; speedup 1.0000x reference)
//
#include <hip/hip_runtime.h>
#include <hip/hip_fp16.h>
#include <utility>
#include <type_traits>

// =====================================================================
// 16-qubit, batch-256 statevector simulator.  R11.
//
// R10 post-mortem: NREG=48 halved spill HBM traffic (70->35.8 MB WRITE)
// but dur flat at 311us.  Pressure 48S+4c+8tmp+addr ~= 68-70 vs the
// immovable 64-VGPR budget -> still spilling in every gate.  R11 makes
// the kernel FIT with margin (one variable: spills -> 0), holding the
// exchange structure (8 barriers/wave-gate) constant:
//   * NREG=40: chunks 0..4 (amps 0..39) in regs; amps 40..63 in 6 LDS
//     granules slds4[6][1024] (uint4 = 4 amps), ds_read/write_b128,
//     conflict-free.
//   * ctab -> global workspace via prekernel (batch-independent!);
//     per-gate coeffs come in as uniform s_load -> SGPRs.  Frees VGPRs,
//     1 KB LDS, and per-gate LDS reads.
//   * xbuf 16 rows (64 KB) unchanged; itab/red OVERLAY xbuf (disjoint
//     lifetimes).  LDS total = 96K + 64K = 163840 B (AITER fmha uses
//     160 KB on gfx950, so the cap is allocatable).
//   * peak pressure ~= 40S + 4c + 8tmp + ~6 addr = 56-58 < 64.
//
// Predicted: FETCH <2MB, WRITE <1MB, scratch 0, dur 311 -> 180-240us if
// spill-bound; if flat ~280-310 -> exchange/barrier-bound => next round
// attacks wave-crossing gate count via GL(16,F2) basis change.
// =====================================================================

constexpr int NREG = 40;   // register-resident amplitudes per thread
constexpr int NGR  = 6;    // LDS granules of 4 amps (amps 40..63)

// ---------------- compile-time GF(2) matrices ----------------
struct M16 { unsigned r[16]; };

constexpr M16 ident() { M16 m{}; for (int i = 0; i < 16; ++i) m.r[i] = 1u << i; return m; }

constexpr M16 ringm(int s) {
  M16 m = ident();
  for (int i = 15; i >= 0; --i) {
    int pc = 15 - i;
    int pt = 15 - ((i + s) & 15);
    m.r[pt] ^= m.r[pc];
  }
  return m;
}

constexpr M16 mmul(M16 A, M16 B) {
  M16 C{};
  for (int p = 0; p < 16; ++p) {
    unsigned v = 0;
    for (int q = 0; q < 16; ++q) if ((A.r[p] >> q) & 1u) v ^= B.r[q];
    C.r[p] = v;
  }
  return C;
}

constexpr M16 minv(M16 A) {
  M16 I = ident();
  for (int col = 0; col < 16; ++col) {
    int piv = -1;
    for (int row = col; row < 16; ++row) if ((A.r[row] >> col) & 1u) { piv = row; break; }
    unsigned t = A.r[piv]; A.r[piv] = A.r[col]; A.r[col] = t;
    t = I.r[piv]; I.r[piv] = I.r[col]; I.r[col] = t;
    for (int row = 0; row < 16; ++row)
      if (row != col && ((A.r[row] >> col) & 1u)) { A.r[row] ^= A.r[col]; I.r[row] ^= I.r[col]; }
  }
  return I;
}

constexpr bool meq(M16 a, M16 b) { for (int i = 0; i < 16; ++i) if (a.r[i] != b.r[i]) return false; return true; }
constexpr unsigned colmask(M16 P, int b) { unsigned m = 0; for (int p = 0; p < 16; ++p) m |= ((P.r[p] >> b) & 1u) << p; return m; }
constexpr int popc16(unsigned x) { int c = 0; for (int i = 0; i < 16; ++i) c += (x >> i) & 1; return c; }
constexpr int topbit_pow(unsigned x) { int b = 0; for (int i = 0; i < 16; ++i) if ((x >> i) & 1) b = i; return 1 << b; }

struct Tables { unsigned gm[64]; unsigned gc[64]; unsigned meas[16]; };

constexpr Tables make_tables() {
  Tables T{};
  M16 R1 = ringm(1), R2 = ringm(2);
  M16 P0 = R1;
  M16 P1 = mmul(R1, R1);
  M16 P2 = mmul(P1, R2);
  M16 P3 = mmul(P2, R2);
  M16 P[4] = { P0, P1, P2, P3 };
  for (int k = 0; k < 4; ++k) {
    M16 A = minv(P[k]);
    for (int b = 0; b < 16; ++b) {
      T.gm[k * 16 + b] = colmask(P[k], b);
      T.gc[k * 16 + b] = A.r[b];
    }
  }
  M16 A5 = minv(P[3]);
  for (int w = 0; w < 16; ++w) T.meas[w] = A5.r[15 - w];
  return T;
}

constexpr Tables TB = make_tables();

constexpr bool check_tables() {
  for (int g = 0; g < 64; ++g) if ((popc16(TB.gm[g] & TB.gc[g]) & 1) != 1) return false;
  if (!meq(mmul(ringm(1), minv(ringm(1))), ident())) return false;
  if (!meq(mmul(ringm(2), minv(ringm(2))), ident())) return false;
  return true;
}
static_assert(check_tables(), "GF(2) table inconsistency");
static_assert(sizeof(__half2) == 4, "half2 size");

// ---------------- small device helpers ----------------
template<int N, int I = 0, typename F>
__device__ __forceinline__ void sfor(F&& f) {
  if constexpr (I < N) {
    f(std::integral_constant<int, I>{});
    sfor<N, I + 1>(static_cast<F&&>(f));
  }
}

__device__ __forceinline__ int h2i(__half2 v) { return __builtin_bit_cast(int, v); }
__device__ __forceinline__ __half2 i2h(int v) { return __builtin_bit_cast(__half2, v); }
__device__ __forceinline__ unsigned h2u(__half2 v) { return __builtin_bit_cast(unsigned, v); }
__device__ __forceinline__ __half2 u2h(unsigned v) { return __builtin_bit_cast(__half2, v); }

__device__ __forceinline__ __half2 hswap(__half2 v) { __half2 r; r.x = v.y; r.y = v.x; return r; }

// y = c0*xs + (-1)^T c1*swap(xs) + (-1)^T c2*xp + c3*swap(xp)   (packed fp16)
// (runtime flip f is pre-folded into c1,c2 by the caller via sign-XOR)
template<int T>
__device__ __forceinline__ __half2 upd(__half2 xs, __half2 xp,
                                       __half2 c0, __half2 c1, __half2 c2, __half2 c3) {
  __half2 c1t = c1, c2t = c2;
  if constexpr (T) { c1t = __hneg2(c1); c2t = __hneg2(c2); }
  __half2 y = __hmul2(c0, xs);
  y = __hfma2(c1t, hswap(xs), y);
  y = __hfma2(c2t, xp, y);
  y = __hfma2(c3, hswap(xp), y);
  return y;
}

// partner-value fetch: lx==0 -> same thread; else shfl_xor across lanes
template<int lx>
__device__ __forceinline__ __half2 pget(__half2 v) {
  if constexpr (lx == 0) return v;
  else return i2h(__shfl_xor(h2i(v), lx, 64));
}

// SU(2) for U = Ry(c) Rz(b) Ry(a):  U = [[al, -conj(be)], [be, conj(al)]]
__device__ __forceinline__ void su2_coeffs(float a, float b, float c,
                                           float& are, float& aim, float& bre, float& bim) {
  float sapc, capc, samc, camc, sb, cb;
  __sincosf((a + c) * 0.5f, &sapc, &capc);
  __sincosf((a - c) * 0.5f, &samc, &camc);
  __sincosf(b * 0.5f, &sb, &cb);
  are = cb * capc;
  aim = -sb * camc;
  bre = cb * sapc;
  bim = sb * samc;
}

__device__ __forceinline__ unsigned pkh2(float lo, float hi) {
  return h2u(__floats2half2_rn(lo, hi));
}

__device__ __forceinline__ float2 cmulf(float2 a, float vr, float vi) {
  return make_float2(a.x * vr - a.y * vi, a.x * vi + a.y * vr);
}

// ---------------- LDS-resident state granules ----------------
// slds4[g][tid] holds amps L = 40 + g*4 + e (e = 0..3) packed as uint4.
template<int g4>
__device__ __forceinline__ void ldg(const uint4* slds4, unsigned tid, __half2 (&a)[4]) {
  const uint4 v = slds4[g4 * 1024 + tid];
  a[0] = u2h(v.x); a[1] = u2h(v.y); a[2] = u2h(v.z); a[3] = u2h(v.w);
}
template<int g4>
__device__ __forceinline__ void stg(uint4* slds4, unsigned tid, const __half2 (&a)[4]) {
  slds4[g4 * 1024 + tid] = make_uint4(h2u(a[0]), h2u(a[1]), h2u(a[2]), h2u(a[3]));
}

// ---------------- wave-crossing chunk helpers ----------------
// chunks of 8 amps; chunks 0..4 in regs, chunks 5..7 = LDS granules.
template<int ch, int sb>
__device__ __forceinline__ void stage_chunk(const __half2 (&S)[NREG], unsigned tid,
                                            const uint4* slds4, unsigned* xbuf) {
  if constexpr (ch < 5) {
    sfor<8>([&](auto kk) {
      constexpr int k = decltype(kk)::value;
      xbuf[(sb + k) * 1024 + tid] = h2u(S[ch * 8 + k]);
    });
  } else {
    sfor<2>([&](auto uu) {
      constexpr int u = decltype(uu)::value;
      __half2 a[4];
      ldg<(ch - 5) * 2 + u>(slds4, tid, a);
      sfor<4>([&](auto ee) {
        constexpr int e = decltype(ee)::value;
        xbuf[(sb + u * 4 + e) * 1024 + tid] = h2u(a[e]);
      });
    });
  }
}

template<int ch, int pb, unsigned mLt, unsigned ct>
__device__ __forceinline__ void compute_chunk(__half2 (&S)[NREG], unsigned tid, unsigned ptid,
                                              uint4* slds4, const unsigned* xbuf,
                                              __half2 c0, __half2 c1, __half2 c2, __half2 c3) {
  if constexpr (ch < 5) {
    sfor<8>([&](auto kk) {
      constexpr int k = decltype(kk)::value;
      constexpr int L = ch * 8 + k;
      constexpr int slot = pb + ((L ^ (int)mLt) & 7);
      constexpr int t = popc16(ct & (unsigned)L) & 1;
      const __half2 xp = u2h(xbuf[slot * 1024 + ptid]);
      S[L] = upd<t>(S[L], xp, c0, c1, c2, c3);
    });
  } else {
    sfor<2>([&](auto uu) {
      constexpr int u = decltype(uu)::value;
      constexpr int g = (ch - 5) * 2 + u;
      __half2 a[4];
      ldg<g>(slds4, tid, a);
      sfor<4>([&](auto ee) {
        constexpr int e = decltype(ee)::value;
        constexpr int L = ch * 8 + u * 4 + e;
        constexpr int slot = pb + ((L ^ (int)mLt) & 7);
        constexpr int t = popc16(ct & (unsigned)L) & 1;
        const __half2 xp = u2h(xbuf[slot * 1024 + ptid]);
        a[e] = upd<t>(a[e], xp, c0, c1, c2, c3);
      });
      stg<g>(slds4, tid, a);
    });
  }
}

// ---------------- generalized gate application ----------------
// j = (tid << 6) | L;  L in [0,64): 40 reg amps + 24 LDS amps per thread.
template<int G>
__device__ __forceinline__ void apply_gate(__half2 (&S)[NREG], unsigned tid,
                                           const uint4* __restrict__ ctabg,
                                           uint4* slds4, unsigned* xbuf) {
  constexpr unsigned m  = TB.gm[G];
  constexpr unsigned c  = TB.gc[G];
  constexpr unsigned mL = m & 63u;    // local-bit part of pair mask
  constexpr unsigned mT = m >> 6;     // thread-bit part (lane 0..5, wave 6..9)
  constexpr unsigned mW = m >> 12;    // wave part
  constexpr unsigned mH = mL >> 3;    // chunk part of local mask
  constexpr unsigned mn = mL & 7u;    // within-chunk part
  constexpr int      dt = popc16(c & mL) & 1;  // role flip across local part

  // coefficients: uniform s_load from global; runtime thread-parity flip
  // f folded in as a packed-sign XOR on c1,c2.
  const uint4 cc = ctabg[G];
  const unsigned fm = (__popc((c >> 6) & tid) & 1u) ? 0x80008000u : 0u;
  const __half2 c0 = u2h(cc.x), c1 = u2h(cc.y ^ fm), c2 = u2h(cc.z ^ fm), c3 = u2h(cc.w);

  if constexpr (mW == 0u) {
    // ================= in-thread / lane-crossing =================
    constexpr int lx = (int)mT;        // 0 -> pure local, else shfl distance
    if constexpr (mL == 0u) {
      // self-pair across lanes (lx != 0)
      sfor<NREG>([&](auto ll) {
        constexpr int L = decltype(ll)::value;
        constexpr int t = popc16(c & (unsigned)L) & 1;
        const __half2 xp = pget<lx>(S[L]);
        S[L] = upd<t>(S[L], xp, c0, c1, c2, c3);
      });
      sfor<NGR>([&](auto gg) {
        constexpr int g = decltype(gg)::value;
        __half2 a[4]; ldg<g>(slds4, tid, a);
        sfor<4>([&](auto ee) {
          constexpr int e = decltype(ee)::value;
          constexpr int L = 40 + g * 4 + e;
          constexpr int t = popc16(c & (unsigned)L) & 1;
          const __half2 xp = pget<lx>(a[e]);
          a[e] = upd<t>(a[e], xp, c0, c1, c2, c3);
        });
        stg<g>(slds4, tid, a);
      });
    } else if constexpr (mH == 0u) {
      // in-chunk pairs (xor = mn, 1..7)
      constexpr int tb = topbit_pow(mn);
      sfor<5>([&](auto ch_) {                       // reg chunks
        constexpr int ch = decltype(ch_)::value;
        sfor<8>([&](auto ss) {
          constexpr int s = decltype(ss)::value;
          if constexpr ((s & tb) == 0) {
            constexpr int L0 = ch * 8 + s, L1 = L0 ^ (int)mn;
            constexpr int t = popc16(c & (unsigned)L0) & 1;
            const __half2 x0 = S[L0], x1 = S[L1];
            S[L0] = upd<t>(x0, pget<lx>(x1), c0, c1, c2, c3);
            S[L1] = upd<t ^ dt>(x1, pget<lx>(x0), c0, c1, c2, c3);
          }
        });
      });
      if constexpr (mn < 4u) {
        // within-granule pairs
        sfor<NGR>([&](auto gg) {
          constexpr int g = decltype(gg)::value;
          __half2 a[4]; ldg<g>(slds4, tid, a);
          sfor<4>([&](auto ee) {
            constexpr int e = decltype(ee)::value;
            if constexpr ((e & tb) == 0) {
              constexpr int e1 = e ^ (int)mn;
              constexpr int L0 = 40 + g * 4 + e;
              constexpr int t = popc16(c & (unsigned)L0) & 1;
              const __half2 x0 = a[e], x1 = a[e1];
              a[e]  = upd<t>(x0, pget<lx>(x1), c0, c1, c2, c3);
              a[e1] = upd<t ^ dt>(x1, pget<lx>(x0), c0, c1, c2, c3);
            }
          });
          stg<g>(slds4, tid, a);
        });
      } else {
        // cross-granule within chunk: granule pairs (2q, 2q+1)
        sfor<3>([&](auto qq) {
          constexpr int q = decltype(qq)::value;
          constexpr int gA = 2 * q, gB = 2 * q + 1;
          __half2 a[4], b4[4];
          ldg<gA>(slds4, tid, a); ldg<gB>(slds4, tid, b4);
          sfor<4>([&](auto ee) {
            constexpr int e  = decltype(ee)::value;
            constexpr int e2 = e ^ ((int)mn & 3);
            constexpr int L0 = 40 + gA * 4 + e;
            constexpr int t  = popc16(c & (unsigned)L0) & 1;
            const __half2 x0 = a[e], x1 = b4[e2];
            a[e]   = upd<t>(x0, pget<lx>(x1), c0, c1, c2, c3);
            b4[e2] = upd<t ^ dt>(x1, pget<lx>(x0), c0, c1, c2, c3);
          });
          stg<gA>(slds4, tid, a); stg<gB>(slds4, tid, b4);
        });
      }
    } else {
      // chunk pairs (cA, cB = cA^mH)
      constexpr int tbH = topbit_pow(mH);
      sfor<8>([&](auto cc_) {
        constexpr int cA = decltype(cc_)::value;
        if constexpr ((cA & tbH) == 0) {
          constexpr int cB = cA ^ (int)mH;
          if constexpr (cB < 5) {
            // both reg
            sfor<8>([&](auto ss) {
              constexpr int s = decltype(ss)::value;
              constexpr int L0 = cA * 8 + s, L1 = cB * 8 + (s ^ (int)mn);
              constexpr int t = popc16(c & (unsigned)L0) & 1;
              const __half2 x0 = S[L0], x1 = S[L1];
              S[L0] = upd<t>(x0, pget<lx>(x1), c0, c1, c2, c3);
              S[L1] = upd<t ^ dt>(x1, pget<lx>(x0), c0, c1, c2, c3);
            });
          } else if constexpr (cA >= 5) {
            // both LDS: two granule-pairs
            sfor<2>([&](auto uu) {
              constexpr int u  = decltype(uu)::value;
              constexpr int gA = (cA - 5) * 2 + u;
              constexpr int gB = (cB - 5) * 2 + (u ^ ((int)mn >> 2));
              __half2 a[4], b4[4];
              ldg<gA>(slds4, tid, a); ldg<gB>(slds4, tid, b4);
              sfor<4>([&](auto ee) {
                constexpr int e  = decltype(ee)::value;
                constexpr int e2 = e ^ ((int)mn & 3);
                constexpr int L0 = cA * 8 + u * 4 + e;
                constexpr int t  = popc16(c & (unsigned)L0) & 1;
                const __half2 x0 = a[e], x1 = b4[e2];
                a[e]   = upd<t>(x0, pget<lx>(x1), c0, c1, c2, c3);
                b4[e2] = upd<t ^ dt>(x1, pget<lx>(x0), c0, c1, c2, c3);
              });
              stg<gA>(slds4, tid, a); stg<gB>(slds4, tid, b4);
            });
          } else {
            // mixed: cA reg, cB LDS — process by cB granules
            sfor<2>([&](auto uu) {
              constexpr int u  = decltype(uu)::value;
              constexpr int gB = (cB - 5) * 2 + u;
              __half2 b4[4]; ldg<gB>(slds4, tid, b4);
              sfor<4>([&](auto ee) {
                constexpr int e  = decltype(ee)::value;
                constexpr int sB = u * 4 + e;
                constexpr int sA = sB ^ (int)mn;
                constexpr int L0 = cA * 8 + sA;   // reg amp
                constexpr int t  = popc16(c & (unsigned)L0) & 1;
                const __half2 x0 = S[L0], x1 = b4[e];
                S[L0] = upd<t>(x0, pget<lx>(x1), c0, c1, c2, c3);
                b4[e] = upd<t ^ dt>(x1, pget<lx>(x0), c0, c1, c2, c3);
              });
              stg<gB>(slds4, tid, b4);
            });
          }
        }
      });
    }
  } else {
    // ================= wave-crossing: staged xbuf exchange =================
    const unsigned ptid = tid ^ mT;
    if constexpr (mH == 0u) {
      // partner within same chunk; stage chunk pairs (2r, 2r+1)
      sfor<4>([&](auto rr) {
        constexpr int r = decltype(rr)::value;
        stage_chunk<2 * r, 0>(S, tid, slds4, xbuf);
        stage_chunk<2 * r + 1, 8>(S, tid, slds4, xbuf);
        __syncthreads();
        compute_chunk<2 * r,     0, mL, c>(S, tid, ptid, slds4, xbuf, c0, c1, c2, c3);
        compute_chunk<2 * r + 1, 8, mL, c>(S, tid, ptid, slds4, xbuf, c0, c1, c2, c3);
        __syncthreads();
      });
    } else {
      // chunk pairs (cA, cB = cA^mH): stage both, compute from staged
      constexpr int tbH = topbit_pow(mH);
      sfor<8>([&](auto cc_) {
        constexpr int cA = decltype(cc_)::value;
        if constexpr ((cA & tbH) == 0) {
          constexpr int cB = cA ^ (int)mH;
          stage_chunk<cA, 0>(S, tid, slds4, xbuf);
          stage_chunk<cB, 8>(S, tid, slds4, xbuf);
          __syncthreads();
          compute_chunk<cA, 8, mL, c>(S, tid, ptid, slds4, xbuf, c0, c1, c2, c3);
          compute_chunk<cB, 0, mL, c>(S, tid, ptid, slds4, xbuf, c0, c1, c2, c3);
          __syncthreads();
        }
      });
    }
  }
}

// ---------------- coefficient prekernel (batch-independent) ----------------
__global__ void ctab_build(const float* __restrict__ weight, uint4* __restrict__ ctabg) {
  const int g = (int)threadIdx.x;   // 64 threads
  const int k = g >> 4;             // 0..3 -> layers 2..5
  const int bb = g & 15;
  const int w = 15 - bb;            // wire for this logical bit
  const int base = 48 * (k + 1) + 3 * w;
  float are, aim, bre, bim;
  su2_coeffs(weight[base], weight[base + 1], weight[base + 2], are, aim, bre, bim);
  // set0 (role 0): [c0, c1, c2, c3]; set1 = [c0, -c1, -c2, c3]
  ctabg[g] = make_uint4(pkh2(are, are), pkh2(-aim, aim),
                        pkh2(-bre, -bre), pkh2(-bim, bim));
}

// ---------------- main kernel ----------------
__global__ __attribute__((amdgpu_flat_work_group_size(1024, 1024),
                          amdgpu_waves_per_eu(4, 4)))
void qcir_kernel(const float* __restrict__ inputs, const float* __restrict__ weight,
                 float* __restrict__ out, const uint4* __restrict__ ctabg) {
  __shared__ uint4 slds4[NGR * 1024];              // 96 KB thread-private state
  __shared__ __align__(16) unsigned xbuf[16 * 1024]; // 64 KB exchange (itab/red overlay)

  const unsigned tid = threadIdx.x;
  const unsigned b   = blockIdx.x;

  // ---- itab (per-wire (al,be) after enc+layer1), overlaid in xbuf ----
  float4* itab = reinterpret_cast<float4*>(xbuf);
  if (tid < 16) {
    const int w = (int)tid;
    const float a = weight[3 * w] + inputs[b * 16 + w];  // encoding Ry fused in
    float are, aim, bre, bim;
    su2_coeffs(a, weight[3 * w + 1], weight[3 * w + 2], are, aim, bre, bim);
    itab[w] = make_float4(are, aim, bre, bim);           // U|0> = (al, be)
  }
  __syncthreads();

  // ---- init: product state after encoding + layer 1  (A1 = I) ----
  __half2 S[NREG];
  float2 P = make_float2(1.f, 0.f);
#pragma unroll
  for (int p = 6; p <= 15; ++p) {                 // thread-index bits of j
    const int bit = (int)(tid >> (p - 6)) & 1;
    const float4 t = itab[15 - p];
    P = cmulf(P, bit ? t.z : t.x, bit ? t.w : t.y);
  }
  sfor<8>([&](auto hh) {
    constexpr int h = decltype(hh)::value;        // chunk index (local bits 3..5)
    float2 ph = P;
    sfor<3>([&](auto qq) {
      constexpr int q   = decltype(qq)::value;    // p = 3+q
      constexpr int bit = (h >> q) & 1;
      const float4 t = itab[15 - (3 + q)];
      if constexpr (bit) ph = cmulf(ph, t.z, t.w); else ph = cmulf(ph, t.x, t.y);
    });
    if constexpr (h < 5) {
      sfor<8>([&](auto ll) {
        constexpr int l = decltype(ll)::value;    // local bits 0..2
        float2 pl = ph;
        sfor<3>([&](auto qq) {
          constexpr int q   = decltype(qq)::value;
          constexpr int bit = (l >> q) & 1;
          const float4 t = itab[15 - q];
          if constexpr (bit) pl = cmulf(pl, t.z, t.w); else pl = cmulf(pl, t.x, t.y);
        });
        S[h * 8 + l] = __floats2half2_rn(pl.x, pl.y);
      });
    } else {
      __half2 a0[4], a1[4];
      sfor<8>([&](auto ll) {
        constexpr int l = decltype(ll)::value;
        float2 pl = ph;
        sfor<3>([&](auto qq) {
          constexpr int q   = decltype(qq)::value;
          constexpr int bit = (l >> q) & 1;
          const float4 t = itab[15 - q];
          if constexpr (bit) pl = cmulf(pl, t.z, t.w); else pl = cmulf(pl, t.x, t.y);
        });
        const __half2 v = __floats2half2_rn(pl.x, pl.y);
        if constexpr (l < 4) a0[l] = v; else a1[l - 4] = v;
      });
      stg<(h - 5) * 2>(slds4, tid, a0);
      stg<(h - 5) * 2 + 1>(slds4, tid, a1);
    }
  });
  __syncthreads();   // itab (xbuf) must be dead before gates stage into xbuf

  // ---- layers 2..5: 64 generalized gates (rings virtualized) ----
  sfor<64>([&](auto gg) { apply_gate<decltype(gg)::value>(S, tid, ctabg, slds4, xbuf); });

  // ---- measurement: <Z_w> via signed probability sums ----
  float acc[16];
  sfor<16>([&](auto ww) { acc[decltype(ww)::value] = 0.f; });
  sfor<NREG>([&](auto ll) {
    constexpr int L = decltype(ll)::value;
    const float re = __low2float(S[L]);
    const float im = __high2float(S[L]);
    const float p = re * re + im * im;
    sfor<16>([&](auto ww) {
      constexpr int w = decltype(ww)::value;
      constexpr int t = popc16(TB.meas[w] & 63u & (unsigned)L) & 1;
      if constexpr (t) acc[w] -= p; else acc[w] += p;
    });
  });
  sfor<NGR>([&](auto gg4) {
    constexpr int g = decltype(gg4)::value;
    __half2 a[4]; ldg<g>(slds4, tid, a);
    sfor<4>([&](auto ee) {
      constexpr int e = decltype(ee)::value;
      constexpr int L = 40 + g * 4 + e;
      const float re = __low2float(a[e]);
      const float im = __high2float(a[e]);
      const float p = re * re + im * im;
      sfor<16>([&](auto ww) {
        constexpr int w = decltype(ww)::value;
        constexpr int t = popc16(TB.meas[w] & 63u & (unsigned)L) & 1;
        if constexpr (t) acc[w] -= p; else acc[w] += p;
      });
    });
  });
  // red overlays xbuf: all wave-gate xbuf use ended at the last gate barrier
  float* red = reinterpret_cast<float*>(xbuf);
  sfor<16>([&](auto ww) {
    constexpr int w = decltype(ww)::value;
    const unsigned fw = __popc((TB.meas[w] >> 6) & tid) & 1u;
    float z = fw ? -acc[w] : acc[w];
#pragma unroll
    for (int d = 1; d < 64; d <<= 1) z += __shfl_xor(z, d, 64);
    if ((tid & 63u) == 0u) red[(tid >> 6) * 16 + w] = z;
  });
  __syncthreads();
  if (tid < 16) {
    float s = 0.f;
#pragma unroll
    for (int v = 0; v < 16; ++v) s += red[v * 16 + tid];
    out[b * 16 + tid] = 4.f * s;
  }
}

// ---------------- launcher ----------------
extern "C" void kernel_launch(void* const* d_in, const int* in_sizes, int n_in,
                              void* d_out, int out_size, void* d_ws, size_t ws_size,
                              hipStream_t stream) {
  const float* inputs = (const float*)d_in[0];   // (B, 16) f32
  const float* weight = (const float*)d_in[1];   // (240,)  f32
  float* out = (float*)d_out;                    // (B, 16) f32
  const int B = in_sizes[0] / 16;
  uint4* ctabg = reinterpret_cast<uint4*>(d_ws); // 1 KB of workspace
  ctab_build<<<1, 64, 0, stream>>>(weight, ctabg);
  qcir_kernel<<<B, 1024, 0, stream>>>(inputs, weight, out, ctabg);
}

// Round 5
// 367.519 us; speedup vs baseline: 1.0890x; 1.0890x over previous
//
#include <hip/hip_runtime.h>
#include <hip/hip_fp16.h>
#include <utility>
#include <type_traits>

// =====================================================================
// 16-qubit, batch-256 statevector simulator.  R12.
//
// R9/R10/R11 post-mortem: at 1024 threads/block the compiler pins
// VGPR_Count=64 (every attribute ignored or fatal) and spills the state
// no matter how we shave it (70 / 35.8 / 69 MB scratch HBM traffic).
// Measured gfx950 kernels at 512 threads get 205-249 VGPRs (m214).
// => RESTRUCTURE: 512 threads/block, 128 amps/thread, ALL state in
// registers, __launch_bounds__(512, 2) (2 waves/SIMD budget = 256 VGPR).
//
//  * index layout: j = [local 7 bits][lane 6 bits][wave 3 bits]
//      - mask in local bits  -> in-register pair update (64 pairs)
//      - mask in lane bits   -> __shfl_xor exchange
//      - mask in wave bits   -> staged LDS exchange, 64-amp halves,
//        4 barriers/gate (was 8), 8-wave sync (was 16)
//  * exchange buffer: xbuf4[512][16] uint4 (128 KB), slot-swizzled
//    (slot ^ tid&15) -> uniform b128 bank distribution.
//  * CNOT rings GF(2)-virtualized as before; coeffs via prekernel ->
//    uniform s_load (batch-independent).
//
// Predicted: VGPR >= 140 (decisive), WRITE 69MB -> <1MB, FETCH 55MB ->
// <2MB, bank conflicts ~0, dur 311 -> 120-180us.
// =====================================================================

// ---------------- compile-time GF(2) matrices ----------------
struct M16 { unsigned r[16]; };

constexpr M16 ident() { M16 m{}; for (int i = 0; i < 16; ++i) m.r[i] = 1u << i; return m; }

constexpr M16 ringm(int s) {
  M16 m = ident();
  for (int i = 15; i >= 0; --i) {
    int pc = 15 - i;
    int pt = 15 - ((i + s) & 15);
    m.r[pt] ^= m.r[pc];
  }
  return m;
}

constexpr M16 mmul(M16 A, M16 B) {
  M16 C{};
  for (int p = 0; p < 16; ++p) {
    unsigned v = 0;
    for (int q = 0; q < 16; ++q) if ((A.r[p] >> q) & 1u) v ^= B.r[q];
    C.r[p] = v;
  }
  return C;
}

constexpr M16 minv(M16 A) {
  M16 I = ident();
  for (int col = 0; col < 16; ++col) {
    int piv = -1;
    for (int row = col; row < 16; ++row) if ((A.r[row] >> col) & 1u) { piv = row; break; }
    unsigned t = A.r[piv]; A.r[piv] = A.r[col]; A.r[col] = t;
    t = I.r[piv]; I.r[piv] = I.r[col]; I.r[col] = t;
    for (int row = 0; row < 16; ++row)
      if (row != col && ((A.r[row] >> col) & 1u)) { A.r[row] ^= A.r[col]; I.r[row] ^= I.r[col]; }
  }
  return I;
}

constexpr bool meq(M16 a, M16 b) { for (int i = 0; i < 16; ++i) if (a.r[i] != b.r[i]) return false; return true; }
constexpr unsigned colmask(M16 P, int b) { unsigned m = 0; for (int p = 0; p < 16; ++p) m |= ((P.r[p] >> b) & 1u) << p; return m; }
constexpr int popc16(unsigned x) { int c = 0; for (int i = 0; i < 16; ++i) c += (x >> i) & 1; return c; }
constexpr int topbit_pow(unsigned x) { int b = 0; for (int i = 0; i < 16; ++i) if ((x >> i) & 1) b = i; return 1 << b; }

struct Tables { unsigned gm[64]; unsigned gc[64]; unsigned meas[16]; };

constexpr Tables make_tables() {
  Tables T{};
  M16 R1 = ringm(1), R2 = ringm(2);
  M16 P0 = R1;
  M16 P1 = mmul(R1, R1);
  M16 P2 = mmul(P1, R2);
  M16 P3 = mmul(P2, R2);
  M16 P[4] = { P0, P1, P2, P3 };
  for (int k = 0; k < 4; ++k) {
    M16 A = minv(P[k]);
    for (int b = 0; b < 16; ++b) {
      T.gm[k * 16 + b] = colmask(P[k], b);
      T.gc[k * 16 + b] = A.r[b];
    }
  }
  M16 A5 = minv(P[3]);
  for (int w = 0; w < 16; ++w) T.meas[w] = A5.r[15 - w];
  return T;
}

constexpr Tables TB = make_tables();

constexpr bool check_tables() {
  for (int g = 0; g < 64; ++g) if ((popc16(TB.gm[g] & TB.gc[g]) & 1) != 1) return false;
  if (!meq(mmul(ringm(1), minv(ringm(1))), ident())) return false;
  if (!meq(mmul(ringm(2), minv(ringm(2))), ident())) return false;
  return true;
}
static_assert(check_tables(), "GF(2) table inconsistency");
static_assert(sizeof(__half2) == 4, "half2 size");

// ---------------- small device helpers ----------------
template<int N, int I = 0, typename F>
__device__ __forceinline__ void sfor(F&& f) {
  if constexpr (I < N) {
    f(std::integral_constant<int, I>{});
    sfor<N, I + 1>(static_cast<F&&>(f));
  }
}

__device__ __forceinline__ int h2i(__half2 v) { return __builtin_bit_cast(int, v); }
__device__ __forceinline__ __half2 i2h(int v) { return __builtin_bit_cast(__half2, v); }
__device__ __forceinline__ unsigned h2u(__half2 v) { return __builtin_bit_cast(unsigned, v); }
__device__ __forceinline__ __half2 u2h(unsigned v) { return __builtin_bit_cast(__half2, v); }

__device__ __forceinline__ __half2 hswap(__half2 v) { __half2 r; r.x = v.y; r.y = v.x; return r; }

// y = c0*xs + (-1)^T c1*swap(xs) + (-1)^T c2*xp + c3*swap(xp)   (packed fp16)
// (runtime flip f is pre-folded into c1,c2 by the caller via sign-XOR;
// the T-negation folds into v_pk_fma neg modifiers)
template<int T>
__device__ __forceinline__ __half2 upd(__half2 xs, __half2 xp,
                                       __half2 c0, __half2 c1, __half2 c2, __half2 c3) {
  __half2 c1t = c1, c2t = c2;
  if constexpr (T) { c1t = __hneg2(c1); c2t = __hneg2(c2); }
  __half2 y = __hmul2(c0, xs);
  y = __hfma2(c1t, hswap(xs), y);
  y = __hfma2(c2t, xp, y);
  y = __hfma2(c3, hswap(xp), y);
  return y;
}

// SU(2) for U = Ry(c) Rz(b) Ry(a):  U = [[al, -conj(be)], [be, conj(al)]]
__device__ __forceinline__ void su2_coeffs(float a, float b, float c,
                                           float& are, float& aim, float& bre, float& bim) {
  float sapc, capc, samc, camc, sb, cb;
  __sincosf((a + c) * 0.5f, &sapc, &capc);
  __sincosf((a - c) * 0.5f, &samc, &camc);
  __sincosf(b * 0.5f, &sb, &cb);
  are = cb * capc;
  aim = -sb * camc;
  bre = cb * sapc;
  bim = sb * samc;
}

__device__ __forceinline__ unsigned pkh2(float lo, float hi) {
  return h2u(__floats2half2_rn(lo, hi));
}

__device__ __forceinline__ float2 cmulf(float2 a, float vr, float vi) {
  return make_float2(a.x * vr - a.y * vi, a.x * vi + a.y * vr);
}

// ---------------- generalized gate application ----------------
// j = (tid << 7) | L;  L in [0,128): all 128 __half2 amps in registers.
// tid: 9 bits (lane 0..5, wave 6..8).
template<int G>
__device__ __forceinline__ void apply_gate(__half2 (&S)[128], unsigned tid,
                                           const uint4* __restrict__ ctabg,
                                           uint4* xbuf4) {
  constexpr unsigned m  = TB.gm[G];
  constexpr unsigned c  = TB.gc[G];
  constexpr unsigned mL = m & 127u;   // local-bit part of pair mask (7 bits)
  constexpr unsigned mT = m >> 7;     // thread-bit part (lane 0..5, wave 6..8)
  constexpr unsigned mW = m >> 13;    // wave part (3 bits)
  constexpr int      dt = popc16(c & mL) & 1;  // role flip across local part

  // coefficients: uniform s_load from global; thread-parity flip folded
  // into c1,c2 as a packed-sign XOR.
  const uint4 cc = ctabg[G];
  const unsigned fm = (__popc((c >> 7) & tid) & 1u) ? 0x80008000u : 0u;
  const __half2 c0 = u2h(cc.x), c1 = u2h(cc.y ^ fm), c2 = u2h(cc.z ^ fm), c3 = u2h(cc.w);

  if constexpr (mT == 0u) {
    // ---- pure in-register pairs (64 pairs) ----
    static_assert(dt == 1, "local pair gate must flip role");
    constexpr int hb = topbit_pow(mL);
    sfor<64>([&](auto ii) {
      constexpr int i  = decltype(ii)::value;
      constexpr int L0 = ((i & ~(hb - 1)) << 1) | (i & (hb - 1));
      constexpr int L1 = L0 ^ (int)mL;
      constexpr int t  = popc16(c & (unsigned)L0) & 1;
      const __half2 x0 = S[L0], x1 = S[L1];
      S[L0] = upd<t>(x0, x1, c0, c1, c2, c3);
      S[L1] = upd<t ^ dt>(x1, x0, c0, c1, c2, c3);
    });
  } else if constexpr (mW == 0u) {
    // ---- lane-crossing: shfl_xor within the 64-lane wave ----
    constexpr int lx = (int)mT;       // 1..63
    if constexpr (mL == 0u) {
      sfor<128>([&](auto ll) {
        constexpr int L = decltype(ll)::value;
        constexpr int t = popc16(c & (unsigned)L) & 1;
        const __half2 xp = i2h(__shfl_xor(h2i(S[L]), lx, 64));
        S[L] = upd<t>(S[L], xp, c0, c1, c2, c3);
      });
    } else {
      constexpr int hb = topbit_pow(mL);
      sfor<64>([&](auto ii) {
        constexpr int i  = decltype(ii)::value;
        constexpr int L0 = ((i & ~(hb - 1)) << 1) | (i & (hb - 1));
        constexpr int L1 = L0 ^ (int)mL;
        constexpr int t  = popc16(c & (unsigned)L0) & 1;
        const __half2 x0 = S[L0], x1 = S[L1];
        const __half2 xp0 = i2h(__shfl_xor(h2i(x1), lx, 64)); // partner's L1 -> my L0
        const __half2 xp1 = i2h(__shfl_xor(h2i(x0), lx, 64)); // partner's L0 -> my L1
        S[L0] = upd<t>(x0, xp0, c0, c1, c2, c3);
        S[L1] = upd<t ^ dt>(x1, xp1, c0, c1, c2, c3);
      });
    }
  } else {
    // ---- wave-crossing: staged LDS exchange, 64 amps (16 uint4 slots)
    // per iteration, 2 iterations x 2 barriers = 4 barriers per gate ----
    const unsigned ptid = tid ^ (unsigned)mT;
    const unsigned swz  = tid & 15u;    // slot swizzle (own row)
    const unsigned pswz = ptid & 15u;   // slot swizzle (partner row)
    constexpr unsigned hc4 = mL >> 2;   // group-xor (groups of 4 amps)
    constexpr int      mn2 = (int)(mL & 3u);  // elem-xor within group
    if constexpr (hc4 == 0u) {
      // partner amp within the same 4-amp group
      sfor<2>([&](auto it_) {
        constexpr int it = decltype(it_)::value;
        sfor<16>([&](auto kk) {
          constexpr int k = decltype(kk)::value;
          constexpr int g = it * 16 + k;
          xbuf4[tid * 16u + ((unsigned)k ^ swz)] =
            make_uint4(h2u(S[4*g]), h2u(S[4*g+1]), h2u(S[4*g+2]), h2u(S[4*g+3]));
        });
        __syncthreads();
        sfor<16>([&](auto kk) {
          constexpr int k = decltype(kk)::value;
          constexpr int g = it * 16 + k;
          const uint4 pv = xbuf4[ptid * 16u + ((unsigned)k ^ pswz)];
          const unsigned pa[4] = { pv.x, pv.y, pv.z, pv.w };
          sfor<4>([&](auto ee) {
            constexpr int e = decltype(ee)::value;
            constexpr int L = 4*g + e;
            constexpr int t = popc16(c & (unsigned)L) & 1;
            S[L] = upd<t>(S[L], u2h(pa[e ^ mn2]), c0, c1, c2, c3);
          });
        });
        __syncthreads();
      });
    } else {
      // group pairs (gA, gB = gA ^ hc4): 8 pairs per iteration
      constexpr int tbH = topbit_pow(hc4);
      sfor<2>([&](auto it_) {
        constexpr int it = decltype(it_)::value;
        sfor<8>([&](auto kk) {
          constexpr int k  = decltype(kk)::value;
          constexpr int i  = it * 8 + k;
          constexpr int gA = ((i & ~(tbH - 1)) << 1) | (i & (tbH - 1));
          constexpr int gB = gA ^ (int)hc4;
          xbuf4[tid * 16u + ((unsigned)k ^ swz)] =
            make_uint4(h2u(S[4*gA]), h2u(S[4*gA+1]), h2u(S[4*gA+2]), h2u(S[4*gA+3]));
          xbuf4[tid * 16u + ((unsigned)(8 + k) ^ swz)] =
            make_uint4(h2u(S[4*gB]), h2u(S[4*gB+1]), h2u(S[4*gB+2]), h2u(S[4*gB+3]));
        });
        __syncthreads();
        sfor<8>([&](auto kk) {
          constexpr int k  = decltype(kk)::value;
          constexpr int i  = it * 8 + k;
          constexpr int gA = ((i & ~(tbH - 1)) << 1) | (i & (tbH - 1));
          constexpr int gB = gA ^ (int)hc4;
          const uint4 pvb = xbuf4[ptid * 16u + ((unsigned)(8 + k) ^ pswz)];
          const uint4 pva = xbuf4[ptid * 16u + ((unsigned)k ^ pswz)];
          const unsigned qb[4] = { pvb.x, pvb.y, pvb.z, pvb.w };
          const unsigned qa[4] = { pva.x, pva.y, pva.z, pva.w };
          sfor<4>([&](auto ee) {
            constexpr int e = decltype(ee)::value;
            {
              constexpr int L = 4*gA + e;
              constexpr int t = popc16(c & (unsigned)L) & 1;
              S[L] = upd<t>(S[L], u2h(qb[e ^ mn2]), c0, c1, c2, c3);
            }
            {
              constexpr int L = 4*gB + e;
              constexpr int t = popc16(c & (unsigned)L) & 1;
              S[L] = upd<t>(S[L], u2h(qa[e ^ mn2]), c0, c1, c2, c3);
            }
          });
        });
        __syncthreads();
      });
    }
  }
}

// ---------------- coefficient prekernel (batch-independent) ----------------
__global__ void ctab_build(const float* __restrict__ weight, uint4* __restrict__ ctabg) {
  const int g = (int)threadIdx.x;   // 64 threads
  const int k = g >> 4;             // 0..3 -> layers 2..5
  const int bb = g & 15;
  const int w = 15 - bb;            // wire for this logical bit
  const int base = 48 * (k + 1) + 3 * w;
  float are, aim, bre, bim;
  su2_coeffs(weight[base], weight[base + 1], weight[base + 2], are, aim, bre, bim);
  // set0 (role 0): [c0, c1, c2, c3]; set1 = [c0, -c1, -c2, c3]
  ctabg[g] = make_uint4(pkh2(are, are), pkh2(-aim, aim),
                        pkh2(-bre, -bre), pkh2(-bim, bim));
}

// ---------------- main kernel ----------------
// 512 threads (8 waves): measured gfx950 behavior gives 512-thread
// kernels a 2-waves/SIMD register budget (up to 256 VGPR) when asked via
// __launch_bounds__(512, 2).  State S[128] fits in ~145 VGPRs -> no spill.
__global__ void __launch_bounds__(512, 2)
qcir_kernel(const float* __restrict__ inputs, const float* __restrict__ weight,
            float* __restrict__ out, const uint4* __restrict__ ctabg) {
  __shared__ uint4  xbuf4[512 * 16];  // 128 KB exchange staging
  __shared__ float4 itab[16];         // per-wire (al, be) after enc+layer1
  __shared__ float  red[8 * 16];      // reduction scratch (wave x output)

  const unsigned tid = threadIdx.x;   // 9 bits
  const unsigned b   = blockIdx.x;

  // ---- itab: per-wire (al,be) after encoding + layer 1 ----
  if (tid < 16) {
    const int w = (int)tid;
    const float a = weight[3 * w] + inputs[b * 16 + w];  // encoding Ry fused in
    float are, aim, bre, bim;
    su2_coeffs(a, weight[3 * w + 1], weight[3 * w + 2], are, aim, bre, bim);
    itab[w] = make_float4(are, aim, bre, bim);           // U|0> = (al, be)
  }
  __syncthreads();

  // ---- init: product state after encoding + layer 1  (A1 = I) ----
  __half2 S[128];
  float2 P = make_float2(1.f, 0.f);
#pragma unroll
  for (int p = 7; p <= 15; ++p) {                 // thread-index bits of j
    const int bit = (int)(tid >> (p - 7)) & 1;
    const float4 t = itab[15 - p];
    P = cmulf(P, bit ? t.z : t.x, bit ? t.w : t.y);
  }
  sfor<16>([&](auto hh) {
    constexpr int h = decltype(hh)::value;        // L bits 3..6
    float2 ph = P;
    sfor<4>([&](auto qq) {
      constexpr int q   = decltype(qq)::value;    // p = 3+q
      constexpr int bit = (h >> q) & 1;
      const float4 t = itab[12 - q];
      if constexpr (bit) ph = cmulf(ph, t.z, t.w); else ph = cmulf(ph, t.x, t.y);
    });
    sfor<8>([&](auto ll) {
      constexpr int l = decltype(ll)::value;      // L bits 0..2
      float2 pl = ph;
      sfor<3>([&](auto qq) {
        constexpr int q   = decltype(qq)::value;  // p = q
        constexpr int bit = (l >> q) & 1;
        const float4 t = itab[15 - q];
        if constexpr (bit) pl = cmulf(pl, t.z, t.w); else pl = cmulf(pl, t.x, t.y);
      });
      S[h * 8 + l] = __floats2half2_rn(pl.x, pl.y);
    });
  });

  // ---- layers 2..5: 64 generalized gates (rings virtualized) ----
  sfor<64>([&](auto gg) { apply_gate<decltype(gg)::value>(S, tid, ctabg, xbuf4); });

  // ---- measurement: <Z_w> via signed probability sums ----
  float acc[16];
  sfor<16>([&](auto ww) { acc[decltype(ww)::value] = 0.f; });
  sfor<128>([&](auto ll) {
    constexpr int L = decltype(ll)::value;
    const float re = __low2float(S[L]);
    const float im = __high2float(S[L]);
    const float p = re * re + im * im;
    sfor<16>([&](auto ww) {
      constexpr int w = decltype(ww)::value;
      constexpr int t = popc16(TB.meas[w] & 127u & (unsigned)L) & 1;
      if constexpr (t) acc[w] -= p; else acc[w] += p;
    });
  });
  sfor<16>([&](auto ww) {
    constexpr int w = decltype(ww)::value;
    const unsigned fw = __popc((TB.meas[w] >> 7) & tid) & 1u;
    float z = fw ? -acc[w] : acc[w];
#pragma unroll
    for (int d = 1; d < 64; d <<= 1) z += __shfl_xor(z, d, 64);
    if ((tid & 63u) == 0u) red[(tid >> 6) * 16 + w] = z;
  });
  __syncthreads();
  if (tid < 16) {
    float s = 0.f;
#pragma unroll
    for (int v = 0; v < 8; ++v) s += red[v * 16 + tid];
    out[b * 16 + tid] = 4.f * s;
  }
}

// ---------------- launcher ----------------
extern "C" void kernel_launch(void* const* d_in, const int* in_sizes, int n_in,
                              void* d_out, int out_size, void* d_ws, size_t ws_size,
                              hipStream_t stream) {
  const float* inputs = (const float*)d_in[0];   // (B, 16) f32
  const float* weight = (const float*)d_in[1];   // (240,)  f32
  float* out = (float*)d_out;                    // (B, 16) f32
  const int B = in_sizes[0] / 16;
  uint4* ctabg = reinterpret_cast<uint4*>(d_ws); // 1 KB of workspace
  ctab_build<<<1, 64, 0, stream>>>(weight, ctabg);
  qcir_kernel<<<B, 512, 0, stream>>>(inputs, weight, out, ctabg);
}

// Round 6
// 367.423 us; speedup vs baseline: 1.0893x; 1.0003x over previous
//
#include <hip/hip_runtime.h>
#include <hip/hip_fp16.h>
#include <utility>
#include <type_traits>

// =====================================================================
// 16-qubit, batch-256 statevector simulator.  R13.
//
// R12 post-mortem: 512 threads moved the budget 64 -> 128 VGPR, but the
// allocator targets 4 waves/EU (128 = 512/4) even though LDS (132 KB)
// caps the block at 1/CU = 2 waves/EU -- it spills ~12-20 regs to buy
// occupancy the LDS cap forbids.  Scratch churn 137 MB/dispatch -> per-
// XCD working set 17 MB >> 4 MB L2 -> HBM; 137 MB / 335 us = 409 GB/s:
// the duration IS the spill traffic.
//
// R13 (one variable): amdgpu_waves_per_eu(1,2).  max=2 sets a VGPR
// FLOOR (occupancy may not exceed 2 waves/EU -> vgpr >= ~171); min=1
// lifts the cap to 512.  Range [171,512] covers the ~140 live set ->
// zero spill; hardware is LDS-capped at 2 waves/EU anyway, so the fat
// allocation is free.  (__launch_bounds__(512,2) only capped at 256 --
// it never raised the allocator's floor, hence the 128 undercut.)
//
//  * index layout: j = [local 7 bits][lane 6 bits][wave 3 bits]
//      - local-bit mask  -> in-register pair update (64 pairs)
//      - lane-bit mask   -> __shfl_xor exchange
//      - wave-bit mask   -> staged LDS exchange, 64-amp halves,
//        4 barriers/gate, 8-wave sync
//  * exchange buffer: xbuf4[512][16] uint4 (128 KB), slot-swizzled.
//  * CNOT rings GF(2)-virtualized; coeffs via prekernel (batch-indep).
//
// Predicted: VGPR 128 -> >=171 (decisive), WRITE 91MB -> <1MB, FETCH
// 46MB -> <2MB, dur 335 -> 90-160us.  If VGPR stays 128: attribute path
// exhausted, R14 = 96-reg/32-LDS hybrid sized for the 128 budget.
// =====================================================================

// ---------------- compile-time GF(2) matrices ----------------
struct M16 { unsigned r[16]; };

constexpr M16 ident() { M16 m{}; for (int i = 0; i < 16; ++i) m.r[i] = 1u << i; return m; }

constexpr M16 ringm(int s) {
  M16 m = ident();
  for (int i = 15; i >= 0; --i) {
    int pc = 15 - i;
    int pt = 15 - ((i + s) & 15);
    m.r[pt] ^= m.r[pc];
  }
  return m;
}

constexpr M16 mmul(M16 A, M16 B) {
  M16 C{};
  for (int p = 0; p < 16; ++p) {
    unsigned v = 0;
    for (int q = 0; q < 16; ++q) if ((A.r[p] >> q) & 1u) v ^= B.r[q];
    C.r[p] = v;
  }
  return C;
}

constexpr M16 minv(M16 A) {
  M16 I = ident();
  for (int col = 0; col < 16; ++col) {
    int piv = -1;
    for (int row = col; row < 16; ++row) if ((A.r[row] >> col) & 1u) { piv = row; break; }
    unsigned t = A.r[piv]; A.r[piv] = A.r[col]; A.r[col] = t;
    t = I.r[piv]; I.r[piv] = I.r[col]; I.r[col] = t;
    for (int row = 0; row < 16; ++row)
      if (row != col && ((A.r[row] >> col) & 1u)) { A.r[row] ^= A.r[col]; I.r[row] ^= I.r[col]; }
  }
  return I;
}

constexpr bool meq(M16 a, M16 b) { for (int i = 0; i < 16; ++i) if (a.r[i] != b.r[i]) return false; return true; }
constexpr unsigned colmask(M16 P, int b) { unsigned m = 0; for (int p = 0; p < 16; ++p) m |= ((P.r[p] >> b) & 1u) << p; return m; }
constexpr int popc16(unsigned x) { int c = 0; for (int i = 0; i < 16; ++i) c += (x >> i) & 1; return c; }
constexpr int topbit_pow(unsigned x) { int b = 0; for (int i = 0; i < 16; ++i) if ((x >> i) & 1) b = i; return 1 << b; }

struct Tables { unsigned gm[64]; unsigned gc[64]; unsigned meas[16]; };

constexpr Tables make_tables() {
  Tables T{};
  M16 R1 = ringm(1), R2 = ringm(2);
  M16 P0 = R1;
  M16 P1 = mmul(R1, R1);
  M16 P2 = mmul(P1, R2);
  M16 P3 = mmul(P2, R2);
  M16 P[4] = { P0, P1, P2, P3 };
  for (int k = 0; k < 4; ++k) {
    M16 A = minv(P[k]);
    for (int b = 0; b < 16; ++b) {
      T.gm[k * 16 + b] = colmask(P[k], b);
      T.gc[k * 16 + b] = A.r[b];
    }
  }
  M16 A5 = minv(P[3]);
  for (int w = 0; w < 16; ++w) T.meas[w] = A5.r[15 - w];
  return T;
}

constexpr Tables TB = make_tables();

constexpr bool check_tables() {
  for (int g = 0; g < 64; ++g) if ((popc16(TB.gm[g] & TB.gc[g]) & 1) != 1) return false;
  if (!meq(mmul(ringm(1), minv(ringm(1))), ident())) return false;
  if (!meq(mmul(ringm(2), minv(ringm(2))), ident())) return false;
  return true;
}
static_assert(check_tables(), "GF(2) table inconsistency");
static_assert(sizeof(__half2) == 4, "half2 size");

// ---------------- small device helpers ----------------
template<int N, int I = 0, typename F>
__device__ __forceinline__ void sfor(F&& f) {
  if constexpr (I < N) {
    f(std::integral_constant<int, I>{});
    sfor<N, I + 1>(static_cast<F&&>(f));
  }
}

__device__ __forceinline__ int h2i(__half2 v) { return __builtin_bit_cast(int, v); }
__device__ __forceinline__ __half2 i2h(int v) { return __builtin_bit_cast(__half2, v); }
__device__ __forceinline__ unsigned h2u(__half2 v) { return __builtin_bit_cast(unsigned, v); }
__device__ __forceinline__ __half2 u2h(unsigned v) { return __builtin_bit_cast(__half2, v); }

__device__ __forceinline__ __half2 hswap(__half2 v) { __half2 r; r.x = v.y; r.y = v.x; return r; }

// y = c0*xs + (-1)^T c1*swap(xs) + (-1)^T c2*xp + c3*swap(xp)   (packed fp16)
// (runtime flip f is pre-folded into c1,c2 by the caller via sign-XOR;
// the T-negation folds into v_pk_fma neg modifiers)
template<int T>
__device__ __forceinline__ __half2 upd(__half2 xs, __half2 xp,
                                       __half2 c0, __half2 c1, __half2 c2, __half2 c3) {
  __half2 c1t = c1, c2t = c2;
  if constexpr (T) { c1t = __hneg2(c1); c2t = __hneg2(c2); }
  __half2 y = __hmul2(c0, xs);
  y = __hfma2(c1t, hswap(xs), y);
  y = __hfma2(c2t, xp, y);
  y = __hfma2(c3, hswap(xp), y);
  return y;
}

// SU(2) for U = Ry(c) Rz(b) Ry(a):  U = [[al, -conj(be)], [be, conj(al)]]
__device__ __forceinline__ void su2_coeffs(float a, float b, float c,
                                           float& are, float& aim, float& bre, float& bim) {
  float sapc, capc, samc, camc, sb, cb;
  __sincosf((a + c) * 0.5f, &sapc, &capc);
  __sincosf((a - c) * 0.5f, &samc, &camc);
  __sincosf(b * 0.5f, &sb, &cb);
  are = cb * capc;
  aim = -sb * camc;
  bre = cb * sapc;
  bim = sb * samc;
}

__device__ __forceinline__ unsigned pkh2(float lo, float hi) {
  return h2u(__floats2half2_rn(lo, hi));
}

__device__ __forceinline__ float2 cmulf(float2 a, float vr, float vi) {
  return make_float2(a.x * vr - a.y * vi, a.x * vi + a.y * vr);
}

// ---------------- generalized gate application ----------------
// j = (tid << 7) | L;  L in [0,128): all 128 __half2 amps in registers.
// tid: 9 bits (lane 0..5, wave 6..8).
template<int G>
__device__ __forceinline__ void apply_gate(__half2 (&S)[128], unsigned tid,
                                           const uint4* __restrict__ ctabg,
                                           uint4* xbuf4) {
  constexpr unsigned m  = TB.gm[G];
  constexpr unsigned c  = TB.gc[G];
  constexpr unsigned mL = m & 127u;   // local-bit part of pair mask (7 bits)
  constexpr unsigned mT = m >> 7;     // thread-bit part (lane 0..5, wave 6..8)
  constexpr unsigned mW = m >> 13;    // wave part (3 bits)
  constexpr int      dt = popc16(c & mL) & 1;  // role flip across local part

  // coefficients: uniform s_load from global; thread-parity flip folded
  // into c1,c2 as a packed-sign XOR.
  const uint4 cc = ctabg[G];
  const unsigned fm = (__popc((c >> 7) & tid) & 1u) ? 0x80008000u : 0u;
  const __half2 c0 = u2h(cc.x), c1 = u2h(cc.y ^ fm), c2 = u2h(cc.z ^ fm), c3 = u2h(cc.w);

  if constexpr (mT == 0u) {
    // ---- pure in-register pairs (64 pairs) ----
    static_assert(dt == 1, "local pair gate must flip role");
    constexpr int hb = topbit_pow(mL);
    sfor<64>([&](auto ii) {
      constexpr int i  = decltype(ii)::value;
      constexpr int L0 = ((i & ~(hb - 1)) << 1) | (i & (hb - 1));
      constexpr int L1 = L0 ^ (int)mL;
      constexpr int t  = popc16(c & (unsigned)L0) & 1;
      const __half2 x0 = S[L0], x1 = S[L1];
      S[L0] = upd<t>(x0, x1, c0, c1, c2, c3);
      S[L1] = upd<t ^ dt>(x1, x0, c0, c1, c2, c3);
    });
  } else if constexpr (mW == 0u) {
    // ---- lane-crossing: shfl_xor within the 64-lane wave ----
    constexpr int lx = (int)mT;       // 1..63
    if constexpr (mL == 0u) {
      sfor<128>([&](auto ll) {
        constexpr int L = decltype(ll)::value;
        constexpr int t = popc16(c & (unsigned)L) & 1;
        const __half2 xp = i2h(__shfl_xor(h2i(S[L]), lx, 64));
        S[L] = upd<t>(S[L], xp, c0, c1, c2, c3);
      });
    } else {
      constexpr int hb = topbit_pow(mL);
      sfor<64>([&](auto ii) {
        constexpr int i  = decltype(ii)::value;
        constexpr int L0 = ((i & ~(hb - 1)) << 1) | (i & (hb - 1));
        constexpr int L1 = L0 ^ (int)mL;
        constexpr int t  = popc16(c & (unsigned)L0) & 1;
        const __half2 x0 = S[L0], x1 = S[L1];
        const __half2 xp0 = i2h(__shfl_xor(h2i(x1), lx, 64)); // partner's L1 -> my L0
        const __half2 xp1 = i2h(__shfl_xor(h2i(x0), lx, 64)); // partner's L0 -> my L1
        S[L0] = upd<t>(x0, xp0, c0, c1, c2, c3);
        S[L1] = upd<t ^ dt>(x1, xp1, c0, c1, c2, c3);
      });
    }
  } else {
    // ---- wave-crossing: staged LDS exchange, 64 amps (16 uint4 slots)
    // per iteration, 2 iterations x 2 barriers = 4 barriers per gate ----
    const unsigned ptid = tid ^ (unsigned)mT;
    const unsigned swz  = tid & 15u;    // slot swizzle (own row)
    const unsigned pswz = ptid & 15u;   // slot swizzle (partner row)
    constexpr unsigned hc4 = mL >> 2;   // group-xor (groups of 4 amps)
    constexpr int      mn2 = (int)(mL & 3u);  // elem-xor within group
    if constexpr (hc4 == 0u) {
      // partner amp within the same 4-amp group
      sfor<2>([&](auto it_) {
        constexpr int it = decltype(it_)::value;
        sfor<16>([&](auto kk) {
          constexpr int k = decltype(kk)::value;
          constexpr int g = it * 16 + k;
          xbuf4[tid * 16u + ((unsigned)k ^ swz)] =
            make_uint4(h2u(S[4*g]), h2u(S[4*g+1]), h2u(S[4*g+2]), h2u(S[4*g+3]));
        });
        __syncthreads();
        sfor<16>([&](auto kk) {
          constexpr int k = decltype(kk)::value;
          constexpr int g = it * 16 + k;
          const uint4 pv = xbuf4[ptid * 16u + ((unsigned)k ^ pswz)];
          const unsigned pa[4] = { pv.x, pv.y, pv.z, pv.w };
          sfor<4>([&](auto ee) {
            constexpr int e = decltype(ee)::value;
            constexpr int L = 4*g + e;
            constexpr int t = popc16(c & (unsigned)L) & 1;
            S[L] = upd<t>(S[L], u2h(pa[e ^ mn2]), c0, c1, c2, c3);
          });
        });
        __syncthreads();
      });
    } else {
      // group pairs (gA, gB = gA ^ hc4): 8 pairs per iteration
      constexpr int tbH = topbit_pow(hc4);
      sfor<2>([&](auto it_) {
        constexpr int it = decltype(it_)::value;
        sfor<8>([&](auto kk) {
          constexpr int k  = decltype(kk)::value;
          constexpr int i  = it * 8 + k;
          constexpr int gA = ((i & ~(tbH - 1)) << 1) | (i & (tbH - 1));
          constexpr int gB = gA ^ (int)hc4;
          xbuf4[tid * 16u + ((unsigned)k ^ swz)] =
            make_uint4(h2u(S[4*gA]), h2u(S[4*gA+1]), h2u(S[4*gA+2]), h2u(S[4*gA+3]));
          xbuf4[tid * 16u + ((unsigned)(8 + k) ^ swz)] =
            make_uint4(h2u(S[4*gB]), h2u(S[4*gB+1]), h2u(S[4*gB+2]), h2u(S[4*gB+3]));
        });
        __syncthreads();
        sfor<8>([&](auto kk) {
          constexpr int k  = decltype(kk)::value;
          constexpr int i  = it * 8 + k;
          constexpr int gA = ((i & ~(tbH - 1)) << 1) | (i & (tbH - 1));
          constexpr int gB = gA ^ (int)hc4;
          const uint4 pvb = xbuf4[ptid * 16u + ((unsigned)(8 + k) ^ pswz)];
          const uint4 pva = xbuf4[ptid * 16u + ((unsigned)k ^ pswz)];
          const unsigned qb[4] = { pvb.x, pvb.y, pvb.z, pvb.w };
          const unsigned qa[4] = { pva.x, pva.y, pva.z, pva.w };
          sfor<4>([&](auto ee) {
            constexpr int e = decltype(ee)::value;
            {
              constexpr int L = 4*gA + e;
              constexpr int t = popc16(c & (unsigned)L) & 1;
              S[L] = upd<t>(S[L], u2h(qb[e ^ mn2]), c0, c1, c2, c3);
            }
            {
              constexpr int L = 4*gB + e;
              constexpr int t = popc16(c & (unsigned)L) & 1;
              S[L] = upd<t>(S[L], u2h(qa[e ^ mn2]), c0, c1, c2, c3);
            }
          });
        });
        __syncthreads();
      });
    }
  }
}

// ---------------- coefficient prekernel (batch-independent) ----------------
__global__ void ctab_build(const float* __restrict__ weight, uint4* __restrict__ ctabg) {
  const int g = (int)threadIdx.x;   // 64 threads
  const int k = g >> 4;             // 0..3 -> layers 2..5
  const int bb = g & 15;
  const int w = 15 - bb;            // wire for this logical bit
  const int base = 48 * (k + 1) + 3 * w;
  float are, aim, bre, bim;
  su2_coeffs(weight[base], weight[base + 1], weight[base + 2], are, aim, bre, bim);
  // set0 (role 0): [c0, c1, c2, c3]; set1 = [c0, -c1, -c2, c3]
  ctabg[g] = make_uint4(pkh2(are, are), pkh2(-aim, aim),
                        pkh2(-bre, -bre), pkh2(-bim, bim));
}

// ---------------- main kernel ----------------
// 512 threads (8 waves).  amdgpu_waves_per_eu(1,2): max=2 forces the
// VGPR floor past the live set (no spill); min=1 lifts the cap to 512.
// Hardware occupancy is LDS-capped at 1 block = 2 waves/EU regardless,
// so the fat allocation is free.
__global__ __attribute__((amdgpu_flat_work_group_size(512, 512),
                          amdgpu_waves_per_eu(1, 2)))
void qcir_kernel(const float* __restrict__ inputs, const float* __restrict__ weight,
                 float* __restrict__ out, const uint4* __restrict__ ctabg) {
  __shared__ uint4  xbuf4[512 * 16];  // 128 KB exchange staging
  __shared__ float4 itab[16];         // per-wire (al, be) after enc+layer1
  __shared__ float  red[8 * 16];      // reduction scratch (wave x output)

  const unsigned tid = threadIdx.x;   // 9 bits
  const unsigned b   = blockIdx.x;

  // ---- itab: per-wire (al,be) after encoding + layer 1 ----
  if (tid < 16) {
    const int w = (int)tid;
    const float a = weight[3 * w] + inputs[b * 16 + w];  // encoding Ry fused in
    float are, aim, bre, bim;
    su2_coeffs(a, weight[3 * w + 1], weight[3 * w + 2], are, aim, bre, bim);
    itab[w] = make_float4(are, aim, bre, bim);           // U|0> = (al, be)
  }
  __syncthreads();

  // ---- init: product state after encoding + layer 1  (A1 = I) ----
  __half2 S[128];
  float2 P = make_float2(1.f, 0.f);
#pragma unroll
  for (int p = 7; p <= 15; ++p) {                 // thread-index bits of j
    const int bit = (int)(tid >> (p - 7)) & 1;
    const float4 t = itab[15 - p];
    P = cmulf(P, bit ? t.z : t.x, bit ? t.w : t.y);
  }
  sfor<16>([&](auto hh) {
    constexpr int h = decltype(hh)::value;        // L bits 3..6
    float2 ph = P;
    sfor<4>([&](auto qq) {
      constexpr int q   = decltype(qq)::value;    // p = 3+q
      constexpr int bit = (h >> q) & 1;
      const float4 t = itab[12 - q];
      if constexpr (bit) ph = cmulf(ph, t.z, t.w); else ph = cmulf(ph, t.x, t.y);
    });
    sfor<8>([&](auto ll) {
      constexpr int l = decltype(ll)::value;      // L bits 0..2
      float2 pl = ph;
      sfor<3>([&](auto qq) {
        constexpr int q   = decltype(qq)::value;  // p = q
        constexpr int bit = (l >> q) & 1;
        const float4 t = itab[15 - q];
        if constexpr (bit) pl = cmulf(pl, t.z, t.w); else pl = cmulf(pl, t.x, t.y);
      });
      S[h * 8 + l] = __floats2half2_rn(pl.x, pl.y);
    });
  });

  // ---- layers 2..5: 64 generalized gates (rings virtualized) ----
  sfor<64>([&](auto gg) { apply_gate<decltype(gg)::value>(S, tid, ctabg, xbuf4); });

  // ---- measurement: <Z_w> via signed probability sums ----
  float acc[16];
  sfor<16>([&](auto ww) { acc[decltype(ww)::value] = 0.f; });
  sfor<128>([&](auto ll) {
    constexpr int L = decltype(ll)::value;
    const float re = __low2float(S[L]);
    const float im = __high2float(S[L]);
    const float p = re * re + im * im;
    sfor<16>([&](auto ww) {
      constexpr int w = decltype(ww)::value;
      constexpr int t = popc16(TB.meas[w] & 127u & (unsigned)L) & 1;
      if constexpr (t) acc[w] -= p; else acc[w] += p;
    });
  });
  sfor<16>([&](auto ww) {
    constexpr int w = decltype(ww)::value;
    const unsigned fw = __popc((TB.meas[w] >> 7) & tid) & 1u;
    float z = fw ? -acc[w] : acc[w];
#pragma unroll
    for (int d = 1; d < 64; d <<= 1) z += __shfl_xor(z, d, 64);
    if ((tid & 63u) == 0u) red[(tid >> 6) * 16 + w] = z;
  });
  __syncthreads();
  if (tid < 16) {
    float s = 0.f;
#pragma unroll
    for (int v = 0; v < 8; ++v) s += red[v * 16 + tid];
    out[b * 16 + tid] = 4.f * s;
  }
}

// ---------------- launcher ----------------
extern "C" void kernel_launch(void* const* d_in, const int* in_sizes, int n_in,
                              void* d_out, int out_size, void* d_ws, size_t ws_size,
                              hipStream_t stream) {
  const float* inputs = (const float*)d_in[0];   // (B, 16) f32
  const float* weight = (const float*)d_in[1];   // (240,)  f32
  float* out = (float*)d_out;                    // (B, 16) f32
  const int B = in_sizes[0] / 16;
  uint4* ctabg = reinterpret_cast<uint4*>(d_ws); // 1 KB of workspace
  ctab_build<<<1, 64, 0, stream>>>(weight, ctabg);
  qcir_kernel<<<B, 512, 0, stream>>>(inputs, weight, out, ctabg);
}

// Round 7
// 346.753 us; speedup vs baseline: 1.1542x; 1.0596x over previous
//
#include <hip/hip_runtime.h>
#include <hip/hip_fp16.h>
#include <utility>
#include <type_traits>

// =====================================================================
// 16-qubit, batch-256 statevector simulator.  R14.
//
// Hard fact (R6..R13): allocator VGPR budget = 65536/blockDim (64@1024,
// 128@512); NO attribute moves it (waves_per_eu ignored twice,
// num_vgpr fatal).  R12/R13: S[128]+temps ~ 138 vs 128 -> ~137 MB
// scratch churn = the whole 335us.
//
// R14: FIT THE BUDGET.  512 threads; 96 amps in regs + 32 amps in LDS
// granules; peak live ~ 96+4+8+6 = 114 <= 128 (margin 14 vs R11's
// too-thin slices).
//   * state LDS: sg4[8][512] uint4 (64 KB), granule g = amps
//     96+4g..96+4g+3, ds_read/write_b128 conflict-free.
//   * xbuf: 8 uint4 rows (64 KB), slot-swizzled; wave gates stage 32
//     amps/round -> 4 rounds x 2 barriers = 8 barriers/gate (barriers
//     ~100cyc at 1 block/CU -> +~4us total; cheap).
//   * j = [local 7][lane 6][wave 3]; rings GF(2)-virtualized; coeffs
//     via prekernel -> uniform s_load.
//   * measurement in 2 passes of 8 outputs (acc[8] not acc[16]).
//
// Predicted: FETCH 46MB -> <2MB, WRITE 91MB -> <1MB (scratch=0,
// decisive), VGPR<=128, dur 335 -> 110-190us.  If traffic collapses but
// dur>250 -> VALU-bound -> next: op_sel asm to kill hswap (-33% VALU).
// =====================================================================

constexpr int NSR = 96;   // register-resident amplitudes per thread

// ---------------- compile-time GF(2) matrices ----------------
struct M16 { unsigned r[16]; };

constexpr M16 ident() { M16 m{}; for (int i = 0; i < 16; ++i) m.r[i] = 1u << i; return m; }

constexpr M16 ringm(int s) {
  M16 m = ident();
  for (int i = 15; i >= 0; --i) {
    int pc = 15 - i;
    int pt = 15 - ((i + s) & 15);
    m.r[pt] ^= m.r[pc];
  }
  return m;
}

constexpr M16 mmul(M16 A, M16 B) {
  M16 C{};
  for (int p = 0; p < 16; ++p) {
    unsigned v = 0;
    for (int q = 0; q < 16; ++q) if ((A.r[p] >> q) & 1u) v ^= B.r[q];
    C.r[p] = v;
  }
  return C;
}

constexpr M16 minv(M16 A) {
  M16 I = ident();
  for (int col = 0; col < 16; ++col) {
    int piv = -1;
    for (int row = col; row < 16; ++row) if ((A.r[row] >> col) & 1u) { piv = row; break; }
    unsigned t = A.r[piv]; A.r[piv] = A.r[col]; A.r[col] = t;
    t = I.r[piv]; I.r[piv] = I.r[col]; I.r[col] = t;
    for (int row = 0; row < 16; ++row)
      if (row != col && ((A.r[row] >> col) & 1u)) { A.r[row] ^= A.r[col]; I.r[row] ^= I.r[col]; }
  }
  return I;
}

constexpr bool meq(M16 a, M16 b) { for (int i = 0; i < 16; ++i) if (a.r[i] != b.r[i]) return false; return true; }
constexpr unsigned colmask(M16 P, int b) { unsigned m = 0; for (int p = 0; p < 16; ++p) m |= ((P.r[p] >> b) & 1u) << p; return m; }
constexpr int popc16(unsigned x) { int c = 0; for (int i = 0; i < 16; ++i) c += (x >> i) & 1; return c; }
constexpr int topbit_pow(unsigned x) { int b = 0; for (int i = 0; i < 16; ++i) if ((x >> i) & 1) b = i; return 1 << b; }

struct Tables { unsigned gm[64]; unsigned gc[64]; unsigned meas[16]; };

constexpr Tables make_tables() {
  Tables T{};
  M16 R1 = ringm(1), R2 = ringm(2);
  M16 P0 = R1;
  M16 P1 = mmul(R1, R1);
  M16 P2 = mmul(P1, R2);
  M16 P3 = mmul(P2, R2);
  M16 P[4] = { P0, P1, P2, P3 };
  for (int k = 0; k < 4; ++k) {
    M16 A = minv(P[k]);
    for (int b = 0; b < 16; ++b) {
      T.gm[k * 16 + b] = colmask(P[k], b);
      T.gc[k * 16 + b] = A.r[b];
    }
  }
  M16 A5 = minv(P[3]);
  for (int w = 0; w < 16; ++w) T.meas[w] = A5.r[15 - w];
  return T;
}

constexpr Tables TB = make_tables();

constexpr bool check_tables() {
  for (int g = 0; g < 64; ++g) if ((popc16(TB.gm[g] & TB.gc[g]) & 1) != 1) return false;
  if (!meq(mmul(ringm(1), minv(ringm(1))), ident())) return false;
  if (!meq(mmul(ringm(2), minv(ringm(2))), ident())) return false;
  return true;
}
static_assert(check_tables(), "GF(2) table inconsistency");
static_assert(sizeof(__half2) == 4, "half2 size");

// ---------------- small device helpers ----------------
template<int N, int I = 0, typename F>
__device__ __forceinline__ void sfor(F&& f) {
  if constexpr (I < N) {
    f(std::integral_constant<int, I>{});
    sfor<N, I + 1>(static_cast<F&&>(f));
  }
}

__device__ __forceinline__ int h2i(__half2 v) { return __builtin_bit_cast(int, v); }
__device__ __forceinline__ __half2 i2h(int v) { return __builtin_bit_cast(__half2, v); }
__device__ __forceinline__ unsigned h2u(__half2 v) { return __builtin_bit_cast(unsigned, v); }
__device__ __forceinline__ __half2 u2h(unsigned v) { return __builtin_bit_cast(__half2, v); }

__device__ __forceinline__ __half2 hswap(__half2 v) { __half2 r; r.x = v.y; r.y = v.x; return r; }

// y = c0*xs + (-1)^T c1*swap(xs) + (-1)^T c2*xp + c3*swap(xp)   (packed fp16)
template<int T>
__device__ __forceinline__ __half2 upd(__half2 xs, __half2 xp,
                                       __half2 c0, __half2 c1, __half2 c2, __half2 c3) {
  __half2 c1t = c1, c2t = c2;
  if constexpr (T) { c1t = __hneg2(c1); c2t = __hneg2(c2); }
  __half2 y = __hmul2(c0, xs);
  y = __hfma2(c1t, hswap(xs), y);
  y = __hfma2(c2t, xp, y);
  y = __hfma2(c3, hswap(xp), y);
  return y;
}

// partner-value fetch: lx==0 -> same thread; else shfl_xor across lanes
template<int lx>
__device__ __forceinline__ __half2 pget(__half2 v) {
  if constexpr (lx == 0) return v;
  else return i2h(__shfl_xor(h2i(v), lx, 64));
}

// SU(2) for U = Ry(c) Rz(b) Ry(a):  U = [[al, -conj(be)], [be, conj(al)]]
__device__ __forceinline__ void su2_coeffs(float a, float b, float c,
                                           float& are, float& aim, float& bre, float& bim) {
  float sapc, capc, samc, camc, sb, cb;
  __sincosf((a + c) * 0.5f, &sapc, &capc);
  __sincosf((a - c) * 0.5f, &samc, &camc);
  __sincosf(b * 0.5f, &sb, &cb);
  are = cb * capc;
  aim = -sb * camc;
  bre = cb * sapc;
  bim = sb * samc;
}

__device__ __forceinline__ unsigned pkh2(float lo, float hi) {
  return h2u(__floats2half2_rn(lo, hi));
}

__device__ __forceinline__ float2 cmulf(float2 a, float vr, float vi) {
  return make_float2(a.x * vr - a.y * vi, a.x * vi + a.y * vr);
}

// ---------------- LDS-resident state granules ----------------
// sg4[g*512 + tid] holds amps L = 96 + 4g + e (e = 0..3).
template<int g>
__device__ __forceinline__ void ldgS(const uint4* sg4, unsigned tid, __half2 (&a)[4]) {
  const uint4 v = sg4[g * 512 + tid];
  a[0] = u2h(v.x); a[1] = u2h(v.y); a[2] = u2h(v.z); a[3] = u2h(v.w);
}
template<int g>
__device__ __forceinline__ void stgS(uint4* sg4, unsigned tid, const __half2 (&a)[4]) {
  sg4[g * 512 + tid] = make_uint4(h2u(a[0]), h2u(a[1]), h2u(a[2]), h2u(a[3]));
}

// virtual granule G in [0,32): G < 24 -> S[4G..4G+3]; else sg4 granule G-24
template<int G>
__device__ __forceinline__ uint4 load_vg(const __half2 (&S)[NSR], const uint4* sg4, unsigned tid) {
  if constexpr (G < 24)
    return make_uint4(h2u(S[4*G]), h2u(S[4*G+1]), h2u(S[4*G+2]), h2u(S[4*G+3]));
  else
    return sg4[(G - 24) * 512 + tid];
}

// update virtual granule G from staged partner uint4 (elem map e^me)
template<int G, int me, unsigned cm>
__device__ __forceinline__ void upd_vg(__half2 (&S)[NSR], uint4* sg4, unsigned tid, uint4 pv,
                                       __half2 c0, __half2 c1, __half2 c2, __half2 c3) {
  const unsigned q[4] = { pv.x, pv.y, pv.z, pv.w };
  if constexpr (G < 24) {
    sfor<4>([&](auto ee) {
      constexpr int e = decltype(ee)::value;
      constexpr int L = 4 * G + e;
      constexpr int t = popc16(cm & (unsigned)L) & 1;
      S[L] = upd<t>(S[L], u2h(q[e ^ me]), c0, c1, c2, c3);
    });
  } else {
    __half2 a[4]; ldgS<G - 24>(sg4, tid, a);
    sfor<4>([&](auto ee) {
      constexpr int e = decltype(ee)::value;
      constexpr int L = 4 * G + e;
      constexpr int t = popc16(cm & (unsigned)L) & 1;
      a[e] = upd<t>(a[e], u2h(q[e ^ me]), c0, c1, c2, c3);
    });
    stgS<G - 24>(sg4, tid, a);
  }
}

// ---------------- generalized gate application ----------------
// j = (tid << 7) | L;  L in [0,128): 96 reg amps + 32 LDS amps.
template<int G>
__device__ __forceinline__ void apply_gate(__half2 (&S)[NSR], unsigned tid,
                                           const uint4* __restrict__ ctabg,
                                           uint4* sg4, uint4* xbuf4) {
  constexpr unsigned m  = TB.gm[G];
  constexpr unsigned c  = TB.gc[G];
  constexpr unsigned mL = m & 127u;   // local-bit part (7 bits)
  constexpr unsigned mT = m >> 7;     // thread-bit part (lane 0..5, wave 6..8)
  constexpr unsigned mW = m >> 13;    // wave part (3 bits)

  const uint4 cc = ctabg[G];
  const unsigned fm = (__popc((c >> 7) & tid) & 1u) ? 0x80008000u : 0u;
  const __half2 c0 = u2h(cc.x), c1 = u2h(cc.y ^ fm), c2 = u2h(cc.z ^ fm), c3 = u2h(cc.w);

  if constexpr (mW == 0u) {
    // ============ in-thread / lane-crossing (unified via pget) ============
    constexpr int lx = (int)mT;       // 0 -> pure local; else shfl distance
    if constexpr (mL == 0u) {
      // self-position pair across lanes (lx != 0)
      sfor<NSR>([&](auto ll) {
        constexpr int L = decltype(ll)::value;
        constexpr int t = popc16(c & (unsigned)L) & 1;
        S[L] = upd<t>(S[L], pget<lx>(S[L]), c0, c1, c2, c3);
      });
      sfor<8>([&](auto gg) {
        constexpr int g = decltype(gg)::value;
        __half2 a[4]; ldgS<g>(sg4, tid, a);
        sfor<4>([&](auto ee) {
          constexpr int e = decltype(ee)::value;
          constexpr int L = NSR + g * 4 + e;
          constexpr int t = popc16(c & (unsigned)L) & 1;
          a[e] = upd<t>(a[e], pget<lx>(a[e]), c0, c1, c2, c3);
        });
        stgS<g>(sg4, tid, a);
      });
    } else {
      constexpr int hb = topbit_pow(mL);
      // ---- reg-reg pairs ----
      sfor<64>([&](auto ii) {
        constexpr int i  = decltype(ii)::value;
        constexpr int L0 = ((i & ~(hb - 1)) << 1) | (i & (hb - 1));
        constexpr int L1 = L0 ^ (int)mL;
        if constexpr (L1 < NSR) {     // L0 < L1 always
          constexpr int t0 = popc16(c & (unsigned)L0) & 1;
          constexpr int t1 = popc16(c & (unsigned)L1) & 1;
          const __half2 x0 = S[L0], x1 = S[L1];
          S[L0] = upd<t0>(x0, pget<lx>(x1), c0, c1, c2, c3);
          S[L1] = upd<t1>(x1, pget<lx>(x0), c0, c1, c2, c3);
        }
      });
      if constexpr (mL < 32u) {
        // LDS amps pair among themselves
        if constexpr (mL < 4u) {
          // within-granule pairs
          constexpr int tb = topbit_pow(mL);
          sfor<8>([&](auto gg) {
            constexpr int g = decltype(gg)::value;
            __half2 a[4]; ldgS<g>(sg4, tid, a);
            sfor<4>([&](auto ee) {
              constexpr int e = decltype(ee)::value;
              if constexpr ((e & tb) == 0) {
                constexpr int e1 = e ^ (int)mL;
                constexpr int L0 = NSR + g * 4 + e;
                constexpr int L1 = NSR + g * 4 + e1;
                constexpr int t0 = popc16(c & (unsigned)L0) & 1;
                constexpr int t1 = popc16(c & (unsigned)L1) & 1;
                const __half2 x0 = a[e], x1 = a[e1];
                a[e]  = upd<t0>(x0, pget<lx>(x1), c0, c1, c2, c3);
                a[e1] = upd<t1>(x1, pget<lx>(x0), c0, c1, c2, c3);
              }
            });
            stgS<g>(sg4, tid, a);
          });
        } else {
          // granule pairs (gA, gB = gA ^ hg)
          constexpr int hg = (int)(mL >> 2);   // 1..7
          constexpr int tb = topbit_pow((unsigned)hg);
          constexpr int me = (int)(mL & 3u);
          sfor<8>([&](auto ga_) {
            constexpr int gA = decltype(ga_)::value;
            if constexpr ((gA & tb) == 0) {
              constexpr int gB = gA ^ hg;
              __half2 a[4], b4[4];
              ldgS<gA>(sg4, tid, a); ldgS<gB>(sg4, tid, b4);
              sfor<4>([&](auto ee) {
                constexpr int e  = decltype(ee)::value;
                constexpr int e2 = e ^ me;
                constexpr int L0 = NSR + gA * 4 + e;
                constexpr int L1 = NSR + gB * 4 + e2;
                constexpr int t0 = popc16(c & (unsigned)L0) & 1;
                constexpr int t1 = popc16(c & (unsigned)L1) & 1;
                const __half2 x0 = a[e], x1 = b4[e2];
                a[e]   = upd<t0>(x0, pget<lx>(x1), c0, c1, c2, c3);
                b4[e2] = upd<t1>(x1, pget<lx>(x0), c0, c1, c2, c3);
              });
              stgS<gA>(sg4, tid, a); stgS<gB>(sg4, tid, b4);
            }
          });
        }
      } else {
        // mL >= 32: every LDS amp pairs with a reg amp
        sfor<8>([&](auto gg) {
          constexpr int g = decltype(gg)::value;
          __half2 a[4]; ldgS<g>(sg4, tid, a);
          sfor<4>([&](auto ee) {
            constexpr int e  = decltype(ee)::value;
            constexpr int L1 = NSR + g * 4 + e;        // LDS amp
            constexpr int L0 = L1 ^ (int)mL;           // reg partner (< 96)
            static_assert(L0 < NSR, "mixed pair partner must be reg");
            constexpr int t0 = popc16(c & (unsigned)L0) & 1;
            constexpr int t1 = popc16(c & (unsigned)L1) & 1;
            const __half2 xr = S[L0], xl = a[e];
            const __half2 xpr = pget<lx>(xl);          // partner's LDS amp
            const __half2 xpl = pget<lx>(xr);          // partner's reg amp
            S[L0] = upd<t0>(xr, xpr, c0, c1, c2, c3);
            a[e]  = upd<t1>(xl, xpl, c0, c1, c2, c3);
          });
          stgS<g>(sg4, tid, a);
        });
      }
    }
  } else {
    // ============ wave-crossing: xbuf rounds (8 uint4 slots) ============
    const unsigned ptid = tid ^ (unsigned)mT;
    const unsigned swz  = tid & 7u;
    const unsigned pswz = ptid & 7u;
    constexpr unsigned hG = mL >> 2;          // virtual-granule xor (5 bits)
    constexpr int      me = (int)(mL & 3u);
    if constexpr (hG == 0u) {
      // partner in same virtual granule: 4 rounds of 8 consecutive granules
      sfor<4>([&](auto rr) {
        constexpr int r = decltype(rr)::value;
        sfor<8>([&](auto kk) {
          constexpr int k = decltype(kk)::value;
          constexpr int Gv = r * 8 + k;
          xbuf4[tid * 8u + ((unsigned)k ^ swz)] = load_vg<Gv>(S, sg4, tid);
        });
        __syncthreads();
        sfor<8>([&](auto kk) {
          constexpr int k = decltype(kk)::value;
          constexpr int Gv = r * 8 + k;
          const uint4 pv = xbuf4[ptid * 8u + ((unsigned)k ^ pswz)];
          upd_vg<Gv, me, c>(S, sg4, tid, pv, c0, c1, c2, c3);
        });
        __syncthreads();
      });
    } else {
      // granule pairs (gA, gB = gA ^ hG): 4 rounds of 4 pairs
      constexpr int tbG = topbit_pow(hG);
      sfor<4>([&](auto rr) {
        constexpr int r = decltype(rr)::value;
        sfor<4>([&](auto kk) {
          constexpr int k  = decltype(kk)::value;
          constexpr int i  = r * 4 + k;
          constexpr int gA = ((i & ~(tbG - 1)) << 1) | (i & (tbG - 1));
          constexpr int gB = gA ^ (int)hG;
          xbuf4[tid * 8u + ((unsigned)k ^ swz)]       = load_vg<gA>(S, sg4, tid);
          xbuf4[tid * 8u + ((unsigned)(4 + k) ^ swz)] = load_vg<gB>(S, sg4, tid);
        });
        __syncthreads();
        sfor<4>([&](auto kk) {
          constexpr int k  = decltype(kk)::value;
          constexpr int i  = r * 4 + k;
          constexpr int gA = ((i & ~(tbG - 1)) << 1) | (i & (tbG - 1));
          constexpr int gB = gA ^ (int)hG;
          const uint4 pvB = xbuf4[ptid * 8u + ((unsigned)(4 + k) ^ pswz)];
          const uint4 pvA = xbuf4[ptid * 8u + ((unsigned)k ^ pswz)];
          upd_vg<gA, me, c>(S, sg4, tid, pvB, c0, c1, c2, c3);
          upd_vg<gB, me, c>(S, sg4, tid, pvA, c0, c1, c2, c3);
        });
        __syncthreads();
      });
    }
  }
}

// ---------------- coefficient prekernel (batch-independent) ----------------
__global__ void ctab_build(const float* __restrict__ weight, uint4* __restrict__ ctabg) {
  const int g = (int)threadIdx.x;   // 64 threads
  const int k = g >> 4;             // 0..3 -> layers 2..5
  const int bb = g & 15;
  const int w = 15 - bb;            // wire for this logical bit
  const int base = 48 * (k + 1) + 3 * w;
  float are, aim, bre, bim;
  su2_coeffs(weight[base], weight[base + 1], weight[base + 2], are, aim, bre, bim);
  ctabg[g] = make_uint4(pkh2(are, are), pkh2(-aim, aim),
                        pkh2(-bre, -bre), pkh2(-bim, bim));
}

// ---------------- main kernel ----------------
__global__ __attribute__((amdgpu_flat_work_group_size(512, 512)))
void qcir_kernel(const float* __restrict__ inputs, const float* __restrict__ weight,
                 float* __restrict__ out, const uint4* __restrict__ ctabg) {
  __shared__ uint4  sg4[8 * 512];    // 64 KB LDS-resident state (amps 96..127)
  __shared__ uint4  xbuf4[512 * 8];  // 64 KB exchange staging
  __shared__ float4 itab[16];
  __shared__ float  red[8 * 16];

  const unsigned tid = threadIdx.x;   // 9 bits
  const unsigned b   = blockIdx.x;

  // ---- itab: per-wire (al,be) after encoding + layer 1 ----
  if (tid < 16) {
    const int w = (int)tid;
    const float a = weight[3 * w] + inputs[b * 16 + w];
    float are, aim, bre, bim;
    su2_coeffs(a, weight[3 * w + 1], weight[3 * w + 2], are, aim, bre, bim);
    itab[w] = make_float4(are, aim, bre, bim);
  }
  __syncthreads();

  // ---- init: product state after encoding + layer 1  (A1 = I) ----
  __half2 S[NSR];
  float2 P = make_float2(1.f, 0.f);
#pragma unroll
  for (int p = 7; p <= 15; ++p) {
    const int bit = (int)(tid >> (p - 7)) & 1;
    const float4 t = itab[15 - p];
    P = cmulf(P, bit ? t.z : t.x, bit ? t.w : t.y);
  }
  sfor<16>([&](auto hh) {
    constexpr int h = decltype(hh)::value;        // L bits 3..6
    float2 ph = P;
    sfor<4>([&](auto qq) {
      constexpr int q   = decltype(qq)::value;
      constexpr int bit = (h >> q) & 1;
      const float4 t = itab[12 - q];
      if constexpr (bit) ph = cmulf(ph, t.z, t.w); else ph = cmulf(ph, t.x, t.y);
    });
    if constexpr (h < 12) {
      sfor<8>([&](auto ll) {
        constexpr int l = decltype(ll)::value;
        float2 pl = ph;
        sfor<3>([&](auto qq) {
          constexpr int q   = decltype(qq)::value;
          constexpr int bit = (l >> q) & 1;
          const float4 t = itab[15 - q];
          if constexpr (bit) pl = cmulf(pl, t.z, t.w); else pl = cmulf(pl, t.x, t.y);
        });
        S[h * 8 + l] = __floats2half2_rn(pl.x, pl.y);
      });
    } else {
      __half2 a0[4], a1[4];
      sfor<8>([&](auto ll) {
        constexpr int l = decltype(ll)::value;
        float2 pl = ph;
        sfor<3>([&](auto qq) {
          constexpr int q   = decltype(qq)::value;
          constexpr int bit = (l >> q) & 1;
          const float4 t = itab[15 - q];
          if constexpr (bit) pl = cmulf(pl, t.z, t.w); else pl = cmulf(pl, t.x, t.y);
        });
        const __half2 v = __floats2half2_rn(pl.x, pl.y);
        if constexpr (l < 4) a0[l] = v; else a1[l - 4] = v;
      });
      stgS<(h - 12) * 2>(sg4, tid, a0);
      stgS<(h - 12) * 2 + 1>(sg4, tid, a1);
    }
  });
  __syncthreads();

  // ---- layers 2..5: 64 generalized gates (rings virtualized) ----
  sfor<64>([&](auto gg) { apply_gate<decltype(gg)::value>(S, tid, ctabg, sg4, xbuf4); });

  // ---- measurement: <Z_w> in 2 passes of 8 outputs (acc[8] not 16) ----
  sfor<2>([&](auto hf_) {
    constexpr int hf = decltype(hf_)::value;
    float acc[8];
    sfor<8>([&](auto ww) { acc[decltype(ww)::value] = 0.f; });
    sfor<NSR>([&](auto ll) {
      constexpr int L = decltype(ll)::value;
      const float re = __low2float(S[L]);
      const float im = __high2float(S[L]);
      const float p = re * re + im * im;
      sfor<8>([&](auto w8) {
        constexpr int w = hf * 8 + decltype(w8)::value;
        constexpr int t = popc16(TB.meas[w] & 127u & (unsigned)L) & 1;
        if constexpr (t) acc[decltype(w8)::value] -= p; else acc[decltype(w8)::value] += p;
      });
    });
    sfor<8>([&](auto gg) {
      constexpr int g = decltype(gg)::value;
      __half2 a[4]; ldgS<g>(sg4, tid, a);
      sfor<4>([&](auto ee) {
        constexpr int e = decltype(ee)::value;
        constexpr int L = NSR + g * 4 + e;
        const float re = __low2float(a[e]);
        const float im = __high2float(a[e]);
        const float p = re * re + im * im;
        sfor<8>([&](auto w8) {
          constexpr int w = hf * 8 + decltype(w8)::value;
          constexpr int t = popc16(TB.meas[w] & 127u & (unsigned)L) & 1;
          if constexpr (t) acc[decltype(w8)::value] -= p; else acc[decltype(w8)::value] += p;
        });
      });
    });
    sfor<8>([&](auto w8) {
      constexpr int w = hf * 8 + decltype(w8)::value;
      const unsigned fw = __popc((TB.meas[w] >> 7) & tid) & 1u;
      float z = fw ? -acc[decltype(w8)::value] : acc[decltype(w8)::value];
#pragma unroll
      for (int d = 1; d < 64; d <<= 1) z += __shfl_xor(z, d, 64);
      if ((tid & 63u) == 0u) red[(tid >> 6) * 16 + w] = z;
    });
  });
  __syncthreads();
  if (tid < 16) {
    float s = 0.f;
#pragma unroll
    for (int v = 0; v < 8; ++v) s += red[v * 16 + tid];
    out[b * 16 + tid] = 4.f * s;
  }
}

// ---------------- launcher ----------------
extern "C" void kernel_launch(void* const* d_in, const int* in_sizes, int n_in,
                              void* d_out, int out_size, void* d_ws, size_t ws_size,
                              hipStream_t stream) {
  const float* inputs = (const float*)d_in[0];   // (B, 16) f32
  const float* weight = (const float*)d_in[1];   // (240,)  f32
  float* out = (float*)d_out;                    // (B, 16) f32
  const int B = in_sizes[0] / 16;
  uint4* ctabg = reinterpret_cast<uint4*>(d_ws); // 1 KB of workspace
  ctab_build<<<1, 64, 0, stream>>>(weight, ctabg);
  qcir_kernel<<<B, 512, 0, stream>>>(inputs, weight, out, ctabg);
}

// Round 9
// 287.383 us; speedup vs baseline: 1.3927x; 1.2066x over previous
//
#include <hip/hip_runtime.h>
#include <hip/hip_fp16.h>
#include <utility>
#include <type_traits>

// =====================================================================
// 16-qubit, batch-256 statevector simulator.  R16.
//
// R15 ("container failed twice") post-mortem: same failure signature as
// R7/R8, where a novel construct (amdgpu_num_vgpr) killed the build.
// R15's only deltas vs the R14 build that RAN: (a) inline-asm upd as 4
// separate 1-inst asm statements (~32K asm blocks after unrolling),
// (b) stride-9 xbuf (inert).  Suspect: (a) = compile-time blowup.
//
// R16 (one variable): merge upd into a SINGLE asm block (4 insts, one
// "=&v" early-clobber output, 6 inputs) -> 4x fewer asm statements, no
// tied-operand chains.  Semantics identical to R14's verified upd:
//   y = c0*xs + (-1)^T c1*swap(xs) + (-1)^T c2*xp + c3*swap(xp)
//   swap(src1) = op_sel:[0,1,0] op_sel_hi:[1,0,1]; (-1)^T = neg on coeff.
// Everything else identical to R15 (NSR=96, sg4, stride-9 xbuf,
// prekernel coeffs).
//
// Predicted: VALU issue 175 -> ~100us, dur 325 -> 230-270us, bank
// conflicts 6.5M -> <0.5M, VGPR <= 128.  Pre-committed fallback: if the
// container dies again, asm is toxic in any form -> R17 = SoA
// (re,re)/(im,im) packing, zero swaps, zero asm.
// =====================================================================

constexpr int NSR = 96;   // register-resident amplitudes per thread

// ---------------- compile-time GF(2) matrices ----------------
struct M16 { unsigned r[16]; };

constexpr M16 ident() { M16 m{}; for (int i = 0; i < 16; ++i) m.r[i] = 1u << i; return m; }

constexpr M16 ringm(int s) {
  M16 m = ident();
  for (int i = 15; i >= 0; --i) {
    int pc = 15 - i;
    int pt = 15 - ((i + s) & 15);
    m.r[pt] ^= m.r[pc];
  }
  return m;
}

constexpr M16 mmul(M16 A, M16 B) {
  M16 C{};
  for (int p = 0; p < 16; ++p) {
    unsigned v = 0;
    for (int q = 0; q < 16; ++q) if ((A.r[p] >> q) & 1u) v ^= B.r[q];
    C.r[p] = v;
  }
  return C;
}

constexpr M16 minv(M16 A) {
  M16 I = ident();
  for (int col = 0; col < 16; ++col) {
    int piv = -1;
    for (int row = col; row < 16; ++row) if ((A.r[row] >> col) & 1u) { piv = row; break; }
    unsigned t = A.r[piv]; A.r[piv] = A.r[col]; A.r[col] = t;
    t = I.r[piv]; I.r[piv] = I.r[col]; I.r[col] = t;
    for (int row = 0; row < 16; ++row)
      if (row != col && ((A.r[row] >> col) & 1u)) { A.r[row] ^= A.r[col]; I.r[row] ^= I.r[col]; }
  }
  return I;
}

constexpr bool meq(M16 a, M16 b) { for (int i = 0; i < 16; ++i) if (a.r[i] != b.r[i]) return false; return true; }
constexpr unsigned colmask(M16 P, int b) { unsigned m = 0; for (int p = 0; p < 16; ++p) m |= ((P.r[p] >> b) & 1u) << p; return m; }
constexpr int popc16(unsigned x) { int c = 0; for (int i = 0; i < 16; ++i) c += (x >> i) & 1; return c; }
constexpr int topbit_pow(unsigned x) { int b = 0; for (int i = 0; i < 16; ++i) if ((x >> i) & 1) b = i; return 1 << b; }

struct Tables { unsigned gm[64]; unsigned gc[64]; unsigned meas[16]; };

constexpr Tables make_tables() {
  Tables T{};
  M16 R1 = ringm(1), R2 = ringm(2);
  M16 P0 = R1;
  M16 P1 = mmul(R1, R1);
  M16 P2 = mmul(P1, R2);
  M16 P3 = mmul(P2, R2);
  M16 P[4] = { P0, P1, P2, P3 };
  for (int k = 0; k < 4; ++k) {
    M16 A = minv(P[k]);
    for (int b = 0; b < 16; ++b) {
      T.gm[k * 16 + b] = colmask(P[k], b);
      T.gc[k * 16 + b] = A.r[b];
    }
  }
  M16 A5 = minv(P[3]);
  for (int w = 0; w < 16; ++w) T.meas[w] = A5.r[15 - w];
  return T;
}

constexpr Tables TB = make_tables();

constexpr bool check_tables() {
  for (int g = 0; g < 64; ++g) if ((popc16(TB.gm[g] & TB.gc[g]) & 1) != 1) return false;
  if (!meq(mmul(ringm(1), minv(ringm(1))), ident())) return false;
  if (!meq(mmul(ringm(2), minv(ringm(2))), ident())) return false;
  return true;
}
static_assert(check_tables(), "GF(2) table inconsistency");
static_assert(sizeof(__half2) == 4, "half2 size");

// ---------------- small device helpers ----------------
template<int N, int I = 0, typename F>
__device__ __forceinline__ void sfor(F&& f) {
  if constexpr (I < N) {
    f(std::integral_constant<int, I>{});
    sfor<N, I + 1>(static_cast<F&&>(f));
  }
}

__device__ __forceinline__ int h2i(__half2 v) { return __builtin_bit_cast(int, v); }
__device__ __forceinline__ __half2 i2h(int v) { return __builtin_bit_cast(__half2, v); }
__device__ __forceinline__ unsigned h2u(__half2 v) { return __builtin_bit_cast(unsigned, v); }
__device__ __forceinline__ __half2 u2h(unsigned v) { return __builtin_bit_cast(__half2, v); }

// ---- packed-fp16 complex update: ONE asm block, 4 VOP3P instructions ----
// y = c0*xs + (-1)^T c1*swap(xs) + (-1)^T c2*xp + c3*swap(xp)
// swap(src1) = op_sel:[0,1,0] op_sel_hi:[1,0,1]; (-1)^T = neg_lo/neg_hi
// on the coefficient operand.  "=&v" early-clobber: y is written before
// later inputs are read.
template<int T>
__device__ __forceinline__ __half2 upd(__half2 xs_, __half2 xp_,
                                       __half2 c0_, __half2 c1_, __half2 c2_, __half2 c3_) {
  const unsigned xs = h2u(xs_), xp = h2u(xp_);
  const unsigned c0 = h2u(c0_), c1 = h2u(c1_), c2 = h2u(c2_), c3 = h2u(c3_);
  unsigned y;
  if constexpr (T) {
    asm("v_pk_mul_f16 %0, %1, %2\n\t"
        "v_pk_fma_f16 %0, %3, %2, %0 op_sel:[0,1,0] op_sel_hi:[1,0,1] neg_lo:[1,0,0] neg_hi:[1,0,0]\n\t"
        "v_pk_fma_f16 %0, %4, %5, %0 neg_lo:[1,0,0] neg_hi:[1,0,0]\n\t"
        "v_pk_fma_f16 %0, %6, %5, %0 op_sel:[0,1,0] op_sel_hi:[1,0,1]"
        : "=&v"(y)
        : "v"(c0), "v"(xs), "v"(c1), "v"(c2), "v"(xp), "v"(c3));
  } else {
    asm("v_pk_mul_f16 %0, %1, %2\n\t"
        "v_pk_fma_f16 %0, %3, %2, %0 op_sel:[0,1,0] op_sel_hi:[1,0,1]\n\t"
        "v_pk_fma_f16 %0, %4, %5, %0\n\t"
        "v_pk_fma_f16 %0, %6, %5, %0 op_sel:[0,1,0] op_sel_hi:[1,0,1]"
        : "=&v"(y)
        : "v"(c0), "v"(xs), "v"(c1), "v"(c2), "v"(xp), "v"(c3));
  }
  return u2h(y);
}

// partner-value fetch: lx==0 -> same thread; else shfl_xor across lanes
template<int lx>
__device__ __forceinline__ __half2 pget(__half2 v) {
  if constexpr (lx == 0) return v;
  else return i2h(__shfl_xor(h2i(v), lx, 64));
}

// SU(2) for U = Ry(c) Rz(b) Ry(a):  U = [[al, -conj(be)], [be, conj(al)]]
__device__ __forceinline__ void su2_coeffs(float a, float b, float c,
                                           float& are, float& aim, float& bre, float& bim) {
  float sapc, capc, samc, camc, sb, cb;
  __sincosf((a + c) * 0.5f, &sapc, &capc);
  __sincosf((a - c) * 0.5f, &samc, &camc);
  __sincosf(b * 0.5f, &sb, &cb);
  are = cb * capc;
  aim = -sb * camc;
  bre = cb * sapc;
  bim = sb * samc;
}

__device__ __forceinline__ unsigned pkh2(float lo, float hi) {
  return h2u(__floats2half2_rn(lo, hi));
}

__device__ __forceinline__ float2 cmulf(float2 a, float vr, float vi) {
  return make_float2(a.x * vr - a.y * vi, a.x * vi + a.y * vr);
}

// ---------------- LDS-resident state granules ----------------
// sg4[g*512 + tid] holds amps L = 96 + 4g + e (e = 0..3).
template<int g>
__device__ __forceinline__ void ldgS(const uint4* sg4, unsigned tid, __half2 (&a)[4]) {
  const uint4 v = sg4[g * 512 + tid];
  a[0] = u2h(v.x); a[1] = u2h(v.y); a[2] = u2h(v.z); a[3] = u2h(v.w);
}
template<int g>
__device__ __forceinline__ void stgS(uint4* sg4, unsigned tid, const __half2 (&a)[4]) {
  sg4[g * 512 + tid] = make_uint4(h2u(a[0]), h2u(a[1]), h2u(a[2]), h2u(a[3]));
}

// virtual granule G in [0,32): G < 24 -> S[4G..4G+3]; else sg4 granule G-24
template<int G>
__device__ __forceinline__ uint4 load_vg(const __half2 (&S)[NSR], const uint4* sg4, unsigned tid) {
  if constexpr (G < 24)
    return make_uint4(h2u(S[4*G]), h2u(S[4*G+1]), h2u(S[4*G+2]), h2u(S[4*G+3]));
  else
    return sg4[(G - 24) * 512 + tid];
}

// update virtual granule G from staged partner uint4 (elem map e^me)
template<int G, int me, unsigned cm>
__device__ __forceinline__ void upd_vg(__half2 (&S)[NSR], uint4* sg4, unsigned tid, uint4 pv,
                                       __half2 c0, __half2 c1, __half2 c2, __half2 c3) {
  const unsigned q[4] = { pv.x, pv.y, pv.z, pv.w };
  if constexpr (G < 24) {
    sfor<4>([&](auto ee) {
      constexpr int e = decltype(ee)::value;
      constexpr int L = 4 * G + e;
      constexpr int t = popc16(cm & (unsigned)L) & 1;
      S[L] = upd<t>(S[L], u2h(q[e ^ me]), c0, c1, c2, c3);
    });
  } else {
    __half2 a[4]; ldgS<G - 24>(sg4, tid, a);
    sfor<4>([&](auto ee) {
      constexpr int e = decltype(ee)::value;
      constexpr int L = 4 * G + e;
      constexpr int t = popc16(cm & (unsigned)L) & 1;
      a[e] = upd<t>(a[e], u2h(q[e ^ me]), c0, c1, c2, c3);
    });
    stgS<G - 24>(sg4, tid, a);
  }
}

// ---------------- generalized gate application ----------------
// j = (tid << 7) | L;  L in [0,128): 96 reg amps + 32 LDS amps.
template<int G>
__device__ __forceinline__ void apply_gate(__half2 (&S)[NSR], unsigned tid,
                                           const uint4* __restrict__ ctabg,
                                           uint4* sg4, uint4* xbuf4) {
  constexpr unsigned m  = TB.gm[G];
  constexpr unsigned c  = TB.gc[G];
  constexpr unsigned mL = m & 127u;   // local-bit part (7 bits)
  constexpr unsigned mT = m >> 7;     // thread-bit part (lane 0..5, wave 6..8)
  constexpr unsigned mW = m >> 13;    // wave part (3 bits)

  const uint4 cc = ctabg[G];
  const unsigned fm = (__popc((c >> 7) & tid) & 1u) ? 0x80008000u : 0u;
  const __half2 c0 = u2h(cc.x), c1 = u2h(cc.y ^ fm), c2 = u2h(cc.z ^ fm), c3 = u2h(cc.w);

  if constexpr (mW == 0u) {
    // ============ in-thread / lane-crossing (unified via pget) ============
    constexpr int lx = (int)mT;       // 0 -> pure local; else shfl distance
    if constexpr (mL == 0u) {
      // self-position pair across lanes (lx != 0)
      sfor<NSR>([&](auto ll) {
        constexpr int L = decltype(ll)::value;
        constexpr int t = popc16(c & (unsigned)L) & 1;
        S[L] = upd<t>(S[L], pget<lx>(S[L]), c0, c1, c2, c3);
      });
      sfor<8>([&](auto gg) {
        constexpr int g = decltype(gg)::value;
        __half2 a[4]; ldgS<g>(sg4, tid, a);
        sfor<4>([&](auto ee) {
          constexpr int e = decltype(ee)::value;
          constexpr int L = NSR + g * 4 + e;
          constexpr int t = popc16(c & (unsigned)L) & 1;
          a[e] = upd<t>(a[e], pget<lx>(a[e]), c0, c1, c2, c3);
        });
        stgS<g>(sg4, tid, a);
      });
    } else {
      constexpr int hb = topbit_pow(mL);
      // ---- reg-reg pairs ----
      sfor<64>([&](auto ii) {
        constexpr int i  = decltype(ii)::value;
        constexpr int L0 = ((i & ~(hb - 1)) << 1) | (i & (hb - 1));
        constexpr int L1 = L0 ^ (int)mL;
        if constexpr (L1 < NSR) {     // L0 < L1 always
          constexpr int t0 = popc16(c & (unsigned)L0) & 1;
          constexpr int t1 = popc16(c & (unsigned)L1) & 1;
          const __half2 x0 = S[L0], x1 = S[L1];
          S[L0] = upd<t0>(x0, pget<lx>(x1), c0, c1, c2, c3);
          S[L1] = upd<t1>(x1, pget<lx>(x0), c0, c1, c2, c3);
        }
      });
      if constexpr (mL < 32u) {
        // LDS amps pair among themselves
        if constexpr (mL < 4u) {
          // within-granule pairs
          constexpr int tb = topbit_pow(mL);
          sfor<8>([&](auto gg) {
            constexpr int g = decltype(gg)::value;
            __half2 a[4]; ldgS<g>(sg4, tid, a);
            sfor<4>([&](auto ee) {
              constexpr int e = decltype(ee)::value;
              if constexpr ((e & tb) == 0) {
                constexpr int e1 = e ^ (int)mL;
                constexpr int L0 = NSR + g * 4 + e;
                constexpr int L1 = NSR + g * 4 + e1;
                constexpr int t0 = popc16(c & (unsigned)L0) & 1;
                constexpr int t1 = popc16(c & (unsigned)L1) & 1;
                const __half2 x0 = a[e], x1 = a[e1];
                a[e]  = upd<t0>(x0, pget<lx>(x1), c0, c1, c2, c3);
                a[e1] = upd<t1>(x1, pget<lx>(x0), c0, c1, c2, c3);
              }
            });
            stgS<g>(sg4, tid, a);
          });
        } else {
          // granule pairs (gA, gB = gA ^ hg)
          constexpr int hg = (int)(mL >> 2);   // 1..7
          constexpr int tb = topbit_pow((unsigned)hg);
          constexpr int me = (int)(mL & 3u);
          sfor<8>([&](auto ga_) {
            constexpr int gA = decltype(ga_)::value;
            if constexpr ((gA & tb) == 0) {
              constexpr int gB = gA ^ hg;
              __half2 a[4], b4[4];
              ldgS<gA>(sg4, tid, a); ldgS<gB>(sg4, tid, b4);
              sfor<4>([&](auto ee) {
                constexpr int e  = decltype(ee)::value;
                constexpr int e2 = e ^ me;
                constexpr int L0 = NSR + gA * 4 + e;
                constexpr int L1 = NSR + gB * 4 + e2;
                constexpr int t0 = popc16(c & (unsigned)L0) & 1;
                constexpr int t1 = popc16(c & (unsigned)L1) & 1;
                const __half2 x0 = a[e], x1 = b4[e2];
                a[e]   = upd<t0>(x0, pget<lx>(x1), c0, c1, c2, c3);
                b4[e2] = upd<t1>(x1, pget<lx>(x0), c0, c1, c2, c3);
              });
              stgS<gA>(sg4, tid, a); stgS<gB>(sg4, tid, b4);
            }
          });
        }
      } else {
        // mL >= 32: every LDS amp pairs with a reg amp
        sfor<8>([&](auto gg) {
          constexpr int g = decltype(gg)::value;
          __half2 a[4]; ldgS<g>(sg4, tid, a);
          sfor<4>([&](auto ee) {
            constexpr int e  = decltype(ee)::value;
            constexpr int L1 = NSR + g * 4 + e;        // LDS amp
            constexpr int L0 = L1 ^ (int)mL;           // reg partner (< 96)
            static_assert(L0 < NSR, "mixed pair partner must be reg");
            constexpr int t0 = popc16(c & (unsigned)L0) & 1;
            constexpr int t1 = popc16(c & (unsigned)L1) & 1;
            const __half2 xr = S[L0], xl = a[e];
            const __half2 xpr = pget<lx>(xl);          // partner's LDS amp
            const __half2 xpl = pget<lx>(xr);          // partner's reg amp
            S[L0] = upd<t0>(xr, xpr, c0, c1, c2, c3);
            a[e]  = upd<t1>(xl, xpl, c0, c1, c2, c3);
          });
          stgS<g>(sg4, tid, a);
        });
      }
    }
  } else {
    // ============ wave-crossing: xbuf rounds (8 slots, stride-9 pad) ============
    const unsigned ptid = tid ^ (unsigned)mT;
    constexpr unsigned hG = mL >> 2;          // virtual-granule xor (5 bits)
    constexpr int      me = (int)(mL & 3u);
    if constexpr (hG == 0u) {
      // partner in same virtual granule: 4 rounds of 8 consecutive granules
      sfor<4>([&](auto rr) {
        constexpr int r = decltype(rr)::value;
        sfor<8>([&](auto kk) {
          constexpr int k = decltype(kk)::value;
          constexpr int Gv = r * 8 + k;
          xbuf4[tid * 9u + (unsigned)k] = load_vg<Gv>(S, sg4, tid);
        });
        __syncthreads();
        sfor<8>([&](auto kk) {
          constexpr int k = decltype(kk)::value;
          constexpr int Gv = r * 8 + k;
          const uint4 pv = xbuf4[ptid * 9u + (unsigned)k];
          upd_vg<Gv, me, c>(S, sg4, tid, pv, c0, c1, c2, c3);
        });
        __syncthreads();
      });
    } else {
      // granule pairs (gA, gB = gA ^ hG): 4 rounds of 4 pairs
      constexpr int tbG = topbit_pow(hG);
      sfor<4>([&](auto rr) {
        constexpr int r = decltype(rr)::value;
        sfor<4>([&](auto kk) {
          constexpr int k  = decltype(kk)::value;
          constexpr int i  = r * 4 + k;
          constexpr int gA = ((i & ~(tbG - 1)) << 1) | (i & (tbG - 1));
          constexpr int gB = gA ^ (int)hG;
          xbuf4[tid * 9u + (unsigned)k]       = load_vg<gA>(S, sg4, tid);
          xbuf4[tid * 9u + (unsigned)(4 + k)] = load_vg<gB>(S, sg4, tid);
        });
        __syncthreads();
        sfor<4>([&](auto kk) {
          constexpr int k  = decltype(kk)::value;
          constexpr int i  = r * 4 + k;
          constexpr int gA = ((i & ~(tbG - 1)) << 1) | (i & (tbG - 1));
          constexpr int gB = gA ^ (int)hG;
          const uint4 pvB = xbuf4[ptid * 9u + (unsigned)(4 + k)];
          const uint4 pvA = xbuf4[ptid * 9u + (unsigned)k];
          upd_vg<gA, me, c>(S, sg4, tid, pvB, c0, c1, c2, c3);
          upd_vg<gB, me, c>(S, sg4, tid, pvA, c0, c1, c2, c3);
        });
        __syncthreads();
      });
    }
  }
}

// ---------------- coefficient prekernel (batch-independent) ----------------
__global__ void ctab_build(const float* __restrict__ weight, uint4* __restrict__ ctabg) {
  const int g = (int)threadIdx.x;   // 64 threads
  const int k = g >> 4;             // 0..3 -> layers 2..5
  const int bb = g & 15;
  const int w = 15 - bb;            // wire for this logical bit
  const int base = 48 * (k + 1) + 3 * w;
  float are, aim, bre, bim;
  su2_coeffs(weight[base], weight[base + 1], weight[base + 2], are, aim, bre, bim);
  ctabg[g] = make_uint4(pkh2(are, are), pkh2(-aim, aim),
                        pkh2(-bre, -bre), pkh2(-bim, bim));
}

// ---------------- main kernel ----------------
__global__ __attribute__((amdgpu_flat_work_group_size(512, 512)))
void qcir_kernel(const float* __restrict__ inputs, const float* __restrict__ weight,
                 float* __restrict__ out, const uint4* __restrict__ ctabg) {
  __shared__ uint4  sg4[8 * 512];    // 64 KB LDS-resident state (amps 96..127)
  __shared__ uint4  xbuf4[512 * 9];  // 73.7 KB exchange staging (stride-9 pad)
  __shared__ float4 itab[16];
  __shared__ float  red[8 * 16];

  const unsigned tid = threadIdx.x;   // 9 bits
  const unsigned b   = blockIdx.x;

  // ---- itab: per-wire (al,be) after encoding + layer 1 ----
  if (tid < 16) {
    const int w = (int)tid;
    const float a = weight[3 * w] + inputs[b * 16 + w];
    float are, aim, bre, bim;
    su2_coeffs(a, weight[3 * w + 1], weight[3 * w + 2], are, aim, bre, bim);
    itab[w] = make_float4(are, aim, bre, bim);
  }
  __syncthreads();

  // ---- init: product state after encoding + layer 1  (A1 = I) ----
  __half2 S[NSR];
  float2 P = make_float2(1.f, 0.f);
#pragma unroll
  for (int p = 7; p <= 15; ++p) {
    const int bit = (int)(tid >> (p - 7)) & 1;
    const float4 t = itab[15 - p];
    P = cmulf(P, bit ? t.z : t.x, bit ? t.w : t.y);
  }
  sfor<16>([&](auto hh) {
    constexpr int h = decltype(hh)::value;        // L bits 3..6
    float2 ph = P;
    sfor<4>([&](auto qq) {
      constexpr int q   = decltype(qq)::value;
      constexpr int bit = (h >> q) & 1;
      const float4 t = itab[12 - q];
      if constexpr (bit) ph = cmulf(ph, t.z, t.w); else ph = cmulf(ph, t.x, t.y);
    });
    if constexpr (h < 12) {
      sfor<8>([&](auto ll) {
        constexpr int l = decltype(ll)::value;
        float2 pl = ph;
        sfor<3>([&](auto qq) {
          constexpr int q   = decltype(qq)::value;
          constexpr int bit = (l >> q) & 1;
          const float4 t = itab[15 - q];
          if constexpr (bit) pl = cmulf(pl, t.z, t.w); else pl = cmulf(pl, t.x, t.y);
        });
        S[h * 8 + l] = __floats2half2_rn(pl.x, pl.y);
      });
    } else {
      __half2 a0[4], a1[4];
      sfor<8>([&](auto ll) {
        constexpr int l = decltype(ll)::value;
        float2 pl = ph;
        sfor<3>([&](auto qq) {
          constexpr int q   = decltype(qq)::value;
          constexpr int bit = (l >> q) & 1;
          const float4 t = itab[15 - q];
          if constexpr (bit) pl = cmulf(pl, t.z, t.w); else pl = cmulf(pl, t.x, t.y);
        });
        const __half2 v = __floats2half2_rn(pl.x, pl.y);
        if constexpr (l < 4) a0[l] = v; else a1[l - 4] = v;
      });
      stgS<(h - 12) * 2>(sg4, tid, a0);
      stgS<(h - 12) * 2 + 1>(sg4, tid, a1);
    }
  });
  __syncthreads();

  // ---- layers 2..5: 64 generalized gates (rings virtualized) ----
  sfor<64>([&](auto gg) { apply_gate<decltype(gg)::value>(S, tid, ctabg, sg4, xbuf4); });

  // ---- measurement: <Z_w> in 2 passes of 8 outputs ----
  sfor<2>([&](auto hf_) {
    constexpr int hf = decltype(hf_)::value;
    float acc[8];
    sfor<8>([&](auto ww) { acc[decltype(ww)::value] = 0.f; });
    sfor<NSR>([&](auto ll) {
      constexpr int L = decltype(ll)::value;
      const float re = __low2float(S[L]);
      const float im = __high2float(S[L]);
      const float p = re * re + im * im;
      sfor<8>([&](auto w8) {
        constexpr int w = hf * 8 + decltype(w8)::value;
        constexpr int t = popc16(TB.meas[w] & 127u & (unsigned)L) & 1;
        if constexpr (t) acc[decltype(w8)::value] -= p; else acc[decltype(w8)::value] += p;
      });
    });
    sfor<8>([&](auto gg) {
      constexpr int g = decltype(gg)::value;
      __half2 a[4]; ldgS<g>(sg4, tid, a);
      sfor<4>([&](auto ee) {
        constexpr int e = decltype(ee)::value;
        constexpr int L = NSR + g * 4 + e;
        const float re = __low2float(a[e]);
        const float im = __high2float(a[e]);
        const float p = re * re + im * im;
        sfor<8>([&](auto w8) {
          constexpr int w = hf * 8 + decltype(w8)::value;
          constexpr int t = popc16(TB.meas[w] & 127u & (unsigned)L) & 1;
          if constexpr (t) acc[decltype(w8)::value] -= p; else acc[decltype(w8)::value] += p;
        });
      });
    });
    sfor<8>([&](auto w8) {
      constexpr int w = hf * 8 + decltype(w8)::value;
      const unsigned fw = __popc((TB.meas[w] >> 7) & tid) & 1u;
      float z = fw ? -acc[decltype(w8)::value] : acc[decltype(w8)::value];
#pragma unroll
      for (int d = 1; d < 64; d <<= 1) z += __shfl_xor(z, d, 64);
      if ((tid & 63u) == 0u) red[(tid >> 6) * 16 + w] = z;
    });
  });
  __syncthreads();
  if (tid < 16) {
    float s = 0.f;
#pragma unroll
    for (int v = 0; v < 8; ++v) s += red[v * 16 + tid];
    out[b * 16 + tid] = 4.f * s;
  }
}

// ---------------- launcher ----------------
extern "C" void kernel_launch(void* const* d_in, const int* in_sizes, int n_in,
                              void* d_out, int out_size, void* d_ws, size_t ws_size,
                              hipStream_t stream) {
  const float* inputs = (const float*)d_in[0];   // (B, 16) f32
  const float* weight = (const float*)d_in[1];   // (240,)  f32
  float* out = (float*)d_out;                    // (B, 16) f32
  const int B = in_sizes[0] / 16;
  uint4* ctabg = reinterpret_cast<uint4*>(d_ws); // 1 KB of workspace
  ctab_build<<<1, 64, 0, stream>>>(weight, ctabg);
  qcir_kernel<<<B, 512, 0, stream>>>(inputs, weight, out, ctabg);
}